// Round 2
// baseline (2789.728 us; speedup 1.0000x reference)
//
#include <hip/hip_runtime.h>
#include <math.h>

#define NN 1329
#define FF 130
#define BB 16
#define TT 24
#define HH 15
#define KK 5
#define BT (BB*TT)      // 384
#define G4 (4*HH)       // 60

#define BM 64
#define BK 32
#define NSTEPS ((NN + BK - 1)/BK)   // 42
#define SA 68           // As_t LDS stride (floats): 272B, 16B-aligned rows, free reads
#define SW 132          // Ws LDS stride (floats): 528B, 16B-aligned; 31.9KB/block -> 5 blocks/CU

// ---- workspace layout (float offsets) ----
#define OFS_ROWSUM 0
#define OFS_WPAD   1344
#define OFS_Y1     (OFS_WPAD + NSTEPS*BK*SW)     // 42*32*132 = 177408
#define OFS_Y2     (OFS_Y1 + BT*NN)
#define OFS_WIHT   (OFS_Y2 + BT*NN)
#define OFS_XW     (OFS_WIHT + NN*64)
#define OFS_S      (OFS_XW + BT*64)

__device__ __forceinline__ float sigmoidf(float x) { return 1.f / (1.f + expf(-x)); }

// ---------------- rowsum of A_hat ----------------
__global__ __launch_bounds__(64) void k_rowsum(const float* __restrict__ A, float* __restrict__ rowsum) {
    int m = blockIdx.x;
    int lane = threadIdx.x;
    float acc = 0.f;
    for (int n = lane; n < NN; n += 64) acc += A[(size_t)m*NN + n];
    for (int off = 32; off; off >>= 1) acc += __shfl_down(acc, off, 64);
    if (lane == 0) rowsum[m] = acc;
}

// ---------------- pre-pad W into [NSTEPS][BK][SW], zero-filled tail ----------------
__global__ __launch_bounds__(256) void k_wpad(const float* __restrict__ W, float* __restrict__ Wpad) {
    int idx = blockIdx.x*256 + threadIdx.x;
    if (idx >= NSTEPS*BK*SW) return;
    int step = idx / (BK*SW);
    int rem  = idx - step*(BK*SW);
    int nn   = rem / SW;
    int f    = rem - nn*SW;
    int n    = step*BK + nn;
    Wpad[idx] = (f < FF && n < NN) ? W[n*FF + f] : 0.f;
}

// ---------------- fused GCN layer 1 + weight2 reduction ----------------
// Y1[bt,m] = sum_f relu( sum_n A[m,n]*s[bt,n]*W[n,f] + bias[f]*rowsum[m] ) * w2[f] + bias2
__global__ __launch_bounds__(256) void k_gcn1(
    const float* __restrict__ A, const float* __restrict__ seq,
    const float* __restrict__ Wpad, const float* __restrict__ bias,
    const float* __restrict__ w2, const float* __restrict__ bias2,
    const float* __restrict__ rowsum, float* __restrict__ Y1)
{
    __shared__ __align__(16) float As[BK][SA];   // As[n][m] = A[m0+m][n0+n]*s[n0+n]
    __shared__ __align__(16) float Ws[BK][SW];   // Ws[n][f]
    __shared__ float red[BM][20];
    __shared__ float bias_s[SW];
    __shared__ float w2_s[SW];
    __shared__ float rs_s[BM];

    // block decode: group m-tiles of 8 so each m-panel maps to a fixed XCD (id%8)
    int id = blockIdx.x;
    int mtile, bt;
    if (id < 6144) {
        int g = (id >= 3072) ? 1 : 0;
        int r = id - g*3072;
        mtile = g*8 + (r & 7);
        bt = r >> 3;
    } else {
        int r = id - 6144;
        mtile = 16 + (r % 5);
        bt = r / 5;
    }
    int m0 = mtile * BM;
    const int tid = threadIdx.x;
    const int i  = tid & 15;   // m-group (4 rows each)
    const int j  = tid >> 4;   // f-group (8 cols each)
    const int nn_st = tid & 31;
    const int mg    = tid >> 5; // 0..7

    if (tid < SW) {
        bias_s[tid] = (tid < FF) ? bias[tid] : 0.f;
        w2_s[tid]   = (tid < FF) ? w2[tid]   : 0.f;
    }
    if (tid < BM) {
        int m = m0 + tid;
        rs_s[tid] = (m < NN) ? rowsum[m] : 0.f;
    }

    float acc[4][8];
#pragma unroll
    for (int c = 0; c < 4; c++)
#pragma unroll
        for (int q = 0; q < 8; q++) acc[c][q] = 0.f;
    float acct = 0.f;
    const int mt  = tid & 63;
    const int ftq = tid >> 6;   // tail threads: tid<128 -> ftq in {0,1}

    const float* seqb = seq + (size_t)bt * NN;

    for (int n0 = 0; n0 < NN; n0 += BK) {
        __syncthreads();
        // stage A*s, transposed
        {
            int n = n0 + nn_st;
            float sv = (n < NN) ? seqb[n] : 0.f;
#pragma unroll
            for (int rr = 0; rr < 8; rr++) {
                int mm = rr*8 + mg;
                int m = m0 + mm;
                float av = (m < NN && n < NN) ? A[(size_t)m*NN + n] : 0.f;
                As[nn_st][mm] = av * sv;
            }
        }
        // stage W chunk: clean float4 copy from pre-padded Wpad (1056 float4s)
        {
            const float4* wsrc = (const float4*)(Wpad + (size_t)(n0/BK)*(BK*SW));
            float4* wdst = (float4*)&Ws[0][0];
#pragma unroll
            for (int it = 0; it < 4; it++) wdst[tid + it*256] = wsrc[tid + it*256];
            if (tid < 32) wdst[tid + 1024] = wsrc[tid + 1024];
        }
        __syncthreads();
#pragma unroll 8
        for (int nn = 0; nn < BK; nn++) {
            const float4 a  = *(const float4*)&As[nn][i*4];
            const float4 w0 = *(const float4*)&Ws[nn][j*8];
            const float4 w1 = *(const float4*)&Ws[nn][j*8 + 4];
            float av[4] = {a.x, a.y, a.z, a.w};
            float wv[8] = {w0.x, w0.y, w0.z, w0.w, w1.x, w1.y, w1.z, w1.w};
#pragma unroll
            for (int c = 0; c < 4; c++)
#pragma unroll
                for (int q = 0; q < 8; q++) acc[c][q] = fmaf(av[c], wv[q], acc[c][q]);
        }
        // tail columns f=128,129 (waves 0,1 only — uniform branch)
        if (tid < 128) {
#pragma unroll 8
            for (int nn = 0; nn < BK; nn++)
                acct = fmaf(As[nn][mt], Ws[nn][128 + ftq], acct);
        }
    }

    // epilogue: relu(+bias*rowsum) dot w2, reduce across f-groups
#pragma unroll
    for (int c = 0; c < 4; c++) {
        float rs = rs_s[i*4 + c];
        float part = 0.f;
#pragma unroll
        for (int q = 0; q < 8; q++) {
            int f = j*8 + q;
            float x = acc[c][q] + bias_s[f] * rs;
            part = fmaf(fmaxf(x, 0.f), w2_s[f], part);
        }
        red[i*4 + c][j] = part;
    }
    if (tid < 128) {
        float x = acct + bias_s[128 + ftq] * rs_s[mt];
        red[mt][16 + ftq] = fmaxf(x, 0.f) * w2_s[128 + ftq];
    }
    __syncthreads();
    if (tid < BM) {
        int m = m0 + tid;
        if (m < NN) {
            float sum = 0.f;
#pragma unroll
            for (int jj = 0; jj < 18; jj++) sum += red[tid][jj];
            Y1[(size_t)bt*NN + m] = sum + bias2[0];
        }
    }
}

// ---------------- GCN layer 2: Y2[bt,m] = relu( sum_n A[m,n]*Y1[bt,n] ) ----------------
__global__ __launch_bounds__(256) void k_gcn2(const float* __restrict__ A,
    const float* __restrict__ Y1, float* __restrict__ Y2)
{
    __shared__ __align__(16) float As[BK][SA];
    __shared__ __align__(16) float Ys[BK][SA];
    int mtile = blockIdx.x;
    int bt0 = blockIdx.y * 64;
    int m0 = mtile * BM;
    const int tid = threadIdx.x;
    const int i = tid & 15;    // m-group
    const int j = tid >> 4;    // bt-group
    const int nn_st = tid & 31;
    const int mg    = tid >> 5;

    float acc[4][4];
#pragma unroll
    for (int c = 0; c < 4; c++)
#pragma unroll
        for (int b = 0; b < 4; b++) acc[c][b] = 0.f;

    for (int n0 = 0; n0 < NN; n0 += BK) {
        __syncthreads();
        {
            int n = n0 + nn_st;
#pragma unroll
            for (int rr = 0; rr < 8; rr++) {
                int mm = rr*8 + mg;
                int m = m0 + mm;
                As[nn_st][mm] = (m < NN && n < NN) ? A[(size_t)m*NN + n] : 0.f;
                int bb = rr*8 + mg;
                Ys[nn_st][bb] = (n < NN) ? Y1[(size_t)(bt0 + bb)*NN + n] : 0.f;
            }
        }
        __syncthreads();
#pragma unroll 8
        for (int nn = 0; nn < BK; nn++) {
            const float4 a = *(const float4*)&As[nn][i*4];
            const float4 y = *(const float4*)&Ys[nn][j*4];
            float av[4] = {a.x, a.y, a.z, a.w};
            float yv[4] = {y.x, y.y, y.z, y.w};
#pragma unroll
            for (int c = 0; c < 4; c++)
#pragma unroll
                for (int b = 0; b < 4; b++) acc[c][b] = fmaf(av[c], yv[b], acc[c][b]);
        }
    }
#pragma unroll
    for (int b = 0; b < 4; b++) {
        int btv = bt0 + j*4 + b;
#pragma unroll
        for (int c = 0; c < 4; c++) {
            int m = m0 + i*4 + c;
            if (m < NN) Y2[(size_t)btv*NN + m] = fmaxf(acc[c][b], 0.f);
        }
    }
}

// ---------------- transpose W_ih [60,N] -> [N,64] ----------------
__global__ __launch_bounds__(256) void k_wih_t(const float* __restrict__ Wih, float* __restrict__ WihT) {
    int idx = blockIdx.x*256 + threadIdx.x;
    if (idx < NN*G4) {
        int n = idx / G4;
        int g = idx - n*G4;
        WihT[n*64 + g] = Wih[(size_t)g*NN + n];
    }
}

// ---------------- xW[bt,g] = sum_n Y2[bt,n]*W_ih[g,n] ----------------
__global__ __launch_bounds__(64) void k_xw(const float* __restrict__ Y2,
    const float* __restrict__ WihT, float* __restrict__ xW)
{
    int bt = blockIdx.x;
    int g = threadIdx.x;
    __shared__ __align__(16) float xsh[256];
    float acc = 0.f;
    for (int base = 0; base < NN; base += 256) {
        __syncthreads();
#pragma unroll
        for (int q = 0; q < 4; q++) {
            int n = base + q*64 + g;
            xsh[q*64 + g] = (n < NN) ? Y2[(size_t)bt*NN + n] : 0.f;
        }
        __syncthreads();
        int lim = min(256, NN - base);
#pragma unroll 4
        for (int nn = 0; nn < lim; nn++)
            acc = fmaf(xsh[nn], WihT[(base + nn)*64 + g], acc);
    }
    if (g < G4) xW[bt*64 + g] = acc;
}

// ---------------- LSTM recurrence (single block) + sigmoid(h_last) ----------------
__global__ __launch_bounds__(960) void k_lstm(const float* __restrict__ xW,
    const float* __restrict__ Whh, const float* __restrict__ bih, const float* __restrict__ bhh,
    const float* __restrict__ h0, const float* __restrict__ c0, float* __restrict__ s_out)
{
    __shared__ float h_s[BB][HH], c_s[BB][HH], g_s[BB][G4];
    __shared__ float whh_s[G4][HH];
    __shared__ float bsum[G4];
    int tid = threadIdx.x;
    if (tid < G4*HH) whh_s[tid/HH][tid%HH] = Whh[tid];
    if (tid < G4) bsum[tid] = bih[tid] + bhh[tid];
    if (tid < BB*HH) {
        h_s[tid/HH][tid%HH] = h0[tid];
        c_s[tid/HH][tid%HH] = c0[tid];
    }
    __syncthreads();
    int b  = tid / G4, jg = tid % G4;   // phase 1 (all 960)
    int b2 = tid / HH, k2 = tid % HH;   // phase 2 (first 240)
    for (int t = 0; t < TT; t++) {
        float v = xW[(b*TT + t)*64 + jg] + bsum[jg];
#pragma unroll
        for (int k = 0; k < HH; k++) v = fmaf(whh_s[jg][k], h_s[b][k], v);
        g_s[b][jg] = v;
        __syncthreads();
        if (tid < BB*HH) {
            float ig = sigmoidf(g_s[b2][k2]);
            float fg = sigmoidf(g_s[b2][HH + k2]);
            float gg = tanhf(g_s[b2][2*HH + k2]);
            float og = sigmoidf(g_s[b2][3*HH + k2]);
            float c = fg * c_s[b2][k2] + ig * gg;
            c_s[b2][k2] = c;
            h_s[b2][k2] = og * tanhf(c);
        }
        __syncthreads();
    }
    if (tid < BB*HH) s_out[tid] = sigmoidf(h_s[b2][k2]);
}

// ---------------- K FC heads: out[k,b,n] = tanh(fc_w[k,n,:]·s[b,:] + fc_b[k,n]) ----------------
__global__ __launch_bounds__(256) void k_heads(const float* __restrict__ fc_w,
    const float* __restrict__ fc_b, const float* __restrict__ s, float* __restrict__ out)
{
    __shared__ float s_s[BB*HH];
    int tid = threadIdx.x;
    if (tid < BB*HH) s_s[tid] = s[tid];
    __syncthreads();
    int idx = blockIdx.x*256 + tid;
    if (idx >= KK*BB*NN) return;
    int k = idx / (BB*NN);
    int rem = idx - k*(BB*NN);
    int b = rem / NN;
    int n = rem - b*NN;
    const float* wp = fc_w + ((size_t)k*NN + n)*HH;
    const float* sp = s_s + b*HH;
    float v = fc_b[k*NN + n];
#pragma unroll
    for (int h = 0; h < HH; h++) v = fmaf(wp[h], sp[h], v);
    out[idx] = tanhf(v);
}

extern "C" void kernel_launch(void* const* d_in, const int* in_sizes, int n_in,
                              void* d_out, int out_size, void* d_ws, size_t ws_size,
                              hipStream_t stream) {
    const float* seq   = (const float*)d_in[0];
    const float* A     = (const float*)d_in[1];
    const float* W     = (const float*)d_in[2];
    const float* bias  = (const float*)d_in[3];
    const float* w2    = (const float*)d_in[4];
    const float* bias2 = (const float*)d_in[5];
    const float* Wih   = (const float*)d_in[6];
    const float* Whh   = (const float*)d_in[7];
    const float* bih   = (const float*)d_in[8];
    const float* bhh   = (const float*)d_in[9];
    const float* h0    = (const float*)d_in[10];
    const float* c0    = (const float*)d_in[11];
    const float* fcw   = (const float*)d_in[12];
    const float* fcb   = (const float*)d_in[13];
    float* ws = (float*)d_ws;
    float* rowsum = ws + OFS_ROWSUM;
    float* Wpad   = ws + OFS_WPAD;
    float* Y1     = ws + OFS_Y1;
    float* Y2     = ws + OFS_Y2;
    float* WihT   = ws + OFS_WIHT;
    float* xW     = ws + OFS_XW;
    float* s_sig  = ws + OFS_S;
    float* out = (float*)d_out;

    hipLaunchKernelGGL(k_rowsum, dim3(NN), dim3(64), 0, stream, A, rowsum);
    hipLaunchKernelGGL(k_wpad, dim3((NSTEPS*BK*SW + 255)/256), dim3(256), 0, stream, W, Wpad);
    hipLaunchKernelGGL(k_gcn1, dim3(21*BT), dim3(256), 0, stream, A, seq, Wpad, bias, w2, bias2, rowsum, Y1);
    hipLaunchKernelGGL(k_gcn2, dim3(21, 6), dim3(256), 0, stream, A, Y1, Y2);
    hipLaunchKernelGGL(k_wih_t, dim3((NN*G4 + 255)/256), dim3(256), 0, stream, Wih, WihT);
    hipLaunchKernelGGL(k_xw, dim3(BT), dim3(64), 0, stream, Y2, WihT, xW);
    hipLaunchKernelGGL(k_lstm, dim3(1), dim3(960), 0, stream, xW, Whh, bih, bhh, h0, c0, s_sig);
    hipLaunchKernelGGL(k_heads, dim3((KK*BB*NN + 255)/256), dim3(256), 0, stream, fcw, fcb, s_sig, out);
}

// Round 5
// 816.582 us; speedup vs baseline: 3.4163x; 3.4163x over previous
//
#include <hip/hip_runtime.h>
#include <math.h>

#define NN 1329
#define FF 130
#define BB 16
#define TT 24
#define HH 15
#define KK 5
#define BT (BB*TT)      // 384
#define G4 (4*HH)       // 60

// ---- MFMA gcn1 geometry ----
#define KPAD 1344
#define NKC 42          // k-chunks of 32
#define MFRAG 88        // row-frags of 16 (11 mtiles * 8)
#define NMT 11          // m-tiles of 128 rows
#define NCF 9           // col-frags of 16 (F=130 padded to 144)

// ---- gcn2 (fp32) geometry ----
#define BM 64
#define BK 32
#define SA 68

typedef __attribute__((ext_vector_type(8))) short short8v;   // 8 bf16
typedef __attribute__((ext_vector_type(4))) float f32x4;

// ---- workspace layout (float offsets) ----
#define OFS_ROWSUM 0
#define OFS_SPAD   1408
#define OFS_Y1     (OFS_SPAD + BT*KPAD)
#define OFS_Y2     (OFS_Y1 + BT*NN)
#define OFS_WIHT   (OFS_Y2 + BT*NN)
#define OFS_XW     (OFS_WIHT + NN*64)
#define OFS_S      (OFS_XW + BT*64)
#define OFS_END_F  (OFS_S + 256)
#define ABF_ELEMS  (NKC*MFRAG*64*8)     // 1,892,352 ushorts
#define WBF_ELEMS  (NKC*NCF*64*8)       //   193,536 ushorts

__device__ __forceinline__ float sigmoidf(float x) { return 1.f / (1.f + expf(-x)); }

__device__ __forceinline__ unsigned short bf16rne(float x) {
    unsigned u = __float_as_uint(x);
    return (unsigned short)((u + 0x7fffu + ((u >> 16) & 1u)) >> 16);
}
__device__ __forceinline__ float bf16tof(unsigned short h) {
    return __uint_as_float(((unsigned)h) << 16);
}

__device__ __forceinline__ void gll16(const void* g, void* l) {
    __builtin_amdgcn_global_load_lds((const __attribute__((address_space(1))) unsigned*)g,
                                     (__attribute__((address_space(3))) unsigned*)l, 16, 0, 0);
}

// ---------------- rowsum of A_hat ----------------
__global__ __launch_bounds__(64) void k_rowsum(const float* __restrict__ A, float* __restrict__ rowsum) {
    int m = blockIdx.x;
    int lane = threadIdx.x;
    float acc = 0.f;
    for (int n = lane; n < NN; n += 64) acc += A[(size_t)m*NN + n];
    for (int off = 32; off; off >>= 1) acc += __shfl_down(acc, off, 64);
    if (lane == 0) rowsum[m] = acc;
}

// ---------------- pack A into bf16 MFMA-fragment-linear layout ----------------
// Abf[kcg][MF][l][j] = bf16(A[MF*16 + (l&15)][kcg*32 + (l>>4)*8 + j])
__global__ __launch_bounds__(256) void k_aprep(const float* __restrict__ A, unsigned short* __restrict__ Abf) {
    int s = blockIdx.x*256 + threadIdx.x;
    if (s >= NKC*MFRAG*64) return;
    int l = s & 63;
    int t = s >> 6;
    int mf = t % MFRAG;
    int kcg = t / MFRAG;
    int m = mf*16 + (l & 15);
    int kb = kcg*32 + (l >> 4)*8;
    union { uint4 u4; unsigned short us[8]; } ow;
#pragma unroll
    for (int j = 0; j < 8; j++) {
        int k = kb + j;
        float x = (m < NN && k < NN) ? A[(size_t)m*NN + k] : 0.f;
        ow.us[j] = bf16rne(x);
    }
    *(uint4*)(Abf + (size_t)s*8) = ow.u4;
}

// ---------------- pack W into bf16 B-fragment-linear layout ----------------
// Wbf[kcg][cf][l][j] = bf16(W[kcg*32 + (l>>4)*8 + j][cf*16 + (l&15)])
__global__ __launch_bounds__(256) void k_wprep(const float* __restrict__ W, unsigned short* __restrict__ Wbf) {
    int s = blockIdx.x*256 + threadIdx.x;
    if (s >= NKC*NCF*64) return;
    int l = s & 63;
    int t = s >> 6;
    int cf = t % NCF;
    int kcg = t / NCF;
    int f = cf*16 + (l & 15);
    int kb = kcg*32 + (l >> 4)*8;
    union { uint4 u4; unsigned short us[8]; } ow;
#pragma unroll
    for (int j = 0; j < 8; j++) {
        int k = kb + j;
        float x = (k < NN && f < FF) ? W[(size_t)k*FF + f] : 0.f;
        ow.us[j] = bf16rne(x);
    }
    *(uint4*)(Wbf + (size_t)s*8) = ow.u4;
}

// ---------------- zero-pad seq to [BT][KPAD] ----------------
__global__ __launch_bounds__(256) void k_sprep(const float* __restrict__ seq, float* __restrict__ spad) {
    int idx = blockIdx.x*256 + threadIdx.x;
    if (idx >= BT*KPAD) return;
    int bt = idx / KPAD;
    int k  = idx - bt*KPAD;
    spad[idx] = (k < NN) ? seq[(size_t)bt*NN + k] : 0.f;
}

// ---------------- fused GCN layer 1 (bf16 MFMA) + weight2 reduction ----------------
// Y1[bt,m] = sum_f relu( sum_k A[m,k]*s[bt,k]*W[k,f] + bias[f]*rowsum[m] ) * w2[f] + bias2
__global__ __launch_bounds__(256) void k_gcn1(
    const unsigned short* __restrict__ Abf, const unsigned short* __restrict__ Wbf,
    const float* __restrict__ spad,
    const float* __restrict__ bias, const float* __restrict__ w2, const float* __restrict__ bias2,
    const float* __restrict__ rowsum, float* __restrict__ Y1)
{
    __shared__ __align__(16) short Alds[2*8*64*8];    // [kc][mf][l][8]  16 KB
    __shared__ __align__(16) short Blds[2*NCF*64*8];  // [kc][cf][l][8]  18 KB

    const int id = blockIdx.x;
    const int mt = id / BT;          // m-tile major: concurrent blocks share the A slice
    const int bt = id - mt*BT;
    const int m0 = mt*128;
    const int tid = threadIdx.x;
    const int lane = tid & 63;
    const int wv = tid >> 6;

    f32x4 acc[2][NCF];
#pragma unroll
    for (int rf = 0; rf < 2; rf++)
#pragma unroll
        for (int cf = 0; cf < NCF; cf++) acc[rf][cf] = (f32x4){0.f, 0.f, 0.f, 0.f};

    const float* sb = spad + (size_t)bt*KPAD;

    for (int step = 0; step < 21; ++step) {
        __syncthreads();
        // ---- B stage: async global->LDS, fragment-linear, zero VALU ----
        {
            const unsigned short* wsrc = Wbf + (size_t)step*(2*NCF*64*8);
#pragma unroll
            for (int it = 0; it < 4; ++it) {
                int slot = it*256 + tid;
                gll16(wsrc + (size_t)slot*8, Blds + slot*8);
            }
            if (tid < 128) {
                int slot = 1024 + tid;
                gll16(wsrc + (size_t)slot*8, Blds + slot*8);
            }
        }
        // ---- A stage: load packed bf16, scale by s[k], write LDS ----
#pragma unroll
        for (int it = 0; it < 4; ++it) {
            int s = it*256 + tid;
            int l = s & 63;
            int mf = (s >> 6) & 7;
            int kc = s >> 9;
            int kcg = step*2 + kc;
            const unsigned short* asrc = Abf + ((size_t)(kcg*MFRAG + mt*8 + mf)*64 + l)*8;
            union { uint4 u4; unsigned short us[8]; } ar;
            ar.u4 = *(const uint4*)asrc;
            int kb = kcg*32 + (l >> 4)*8;
            float4 s0 = *(const float4*)(sb + kb);
            float4 s1 = *(const float4*)(sb + kb + 4);
            float sv[8] = {s0.x, s0.y, s0.z, s0.w, s1.x, s1.y, s1.z, s1.w};
            union { uint4 u4; unsigned short us[8]; } ow;
#pragma unroll
            for (int j = 0; j < 8; j++)
                ow.us[j] = bf16rne(bf16tof(ar.us[j]) * sv[j]);
            *(uint4*)(Alds + s*8) = ow.u4;
        }
        __syncthreads();
        // ---- compute: 2 kc x (2 rowfrags x 9 colfrags) MFMA ----
#pragma unroll
        for (int kc = 0; kc < 2; ++kc) {
            short8v b[NCF];
#pragma unroll
            for (int cf = 0; cf < NCF; cf++)
                b[cf] = *(const short8v*)(Blds + ((kc*NCF + cf)*64 + lane)*8);
            short8v a0 = *(const short8v*)(Alds + ((kc*8 + 2*wv    )*64 + lane)*8);
            short8v a1 = *(const short8v*)(Alds + ((kc*8 + 2*wv + 1)*64 + lane)*8);
#pragma unroll
            for (int cf = 0; cf < NCF; cf++) {
                acc[0][cf] = __builtin_amdgcn_mfma_f32_16x16x32_bf16(a0, b[cf], acc[0][cf], 0, 0, 0);
                acc[1][cf] = __builtin_amdgcn_mfma_f32_16x16x32_bf16(a1, b[cf], acc[1][cf], 0, 0, 0);
            }
        }
    }

    // ---- epilogue: relu(X + bias*rowsum) dot w2, butterfly over 16 f-lanes ----
    const int fcol = lane & 15;
    const int rgrp = lane >> 4;
    float bv[NCF], wv2[NCF];
#pragma unroll
    for (int cf = 0; cf < NCF; cf++) {
        int f = cf*16 + fcol;
        bv[cf]  = (f < FF) ? bias[f] : 0.f;
        wv2[cf] = (f < FF) ? w2[f]   : 0.f;
    }
    float b2 = bias2[0];
#pragma unroll
    for (int rf = 0; rf < 2; rf++) {
#pragma unroll
        for (int r = 0; r < 4; r++) {
            int m = m0 + (2*wv + rf)*16 + rgrp*4 + r;
            float rs = (m < NN) ? rowsum[m] : 0.f;
            float p = 0.f;
#pragma unroll
            for (int cf = 0; cf < NCF; cf++)
                p += fmaxf(acc[rf][cf][r] + bv[cf]*rs, 0.f) * wv2[cf];
            p += __shfl_xor(p, 1, 64);
            p += __shfl_xor(p, 2, 64);
            p += __shfl_xor(p, 4, 64);
            p += __shfl_xor(p, 8, 64);
            if (fcol == 0 && m < NN) Y1[(size_t)bt*NN + m] = p + b2;
        }
    }
}

// ---------------- GCN layer 2: Y2[bt,m] = relu( sum_n A[m,n]*Y1[bt,n] ) ----------------
__global__ __launch_bounds__(256) void k_gcn2(const float* __restrict__ A,
    const float* __restrict__ Y1, float* __restrict__ Y2)
{
    __shared__ __align__(16) float As[BK][SA];
    __shared__ __align__(16) float Ys[BK][SA];
    int mtile = blockIdx.x;
    int bt0 = blockIdx.y * 64;
    int m0 = mtile * BM;
    const int tid = threadIdx.x;
    const int i = tid & 15;
    const int j = tid >> 4;
    const int nn_st = tid & 31;
    const int mg    = tid >> 5;

    float acc[4][4];
#pragma unroll
    for (int c = 0; c < 4; c++)
#pragma unroll
        for (int b = 0; b < 4; b++) acc[c][b] = 0.f;

    for (int n0 = 0; n0 < NN; n0 += BK) {
        __syncthreads();
        {
            int n = n0 + nn_st;
#pragma unroll
            for (int rr = 0; rr < 8; rr++) {
                int mm = rr*8 + mg;
                int m = m0 + mm;
                As[nn_st][mm] = (m < NN && n < NN) ? A[(size_t)m*NN + n] : 0.f;
                int bb = rr*8 + mg;
                Ys[nn_st][bb] = (n < NN) ? Y1[(size_t)(bt0 + bb)*NN + n] : 0.f;
            }
        }
        __syncthreads();
#pragma unroll 8
        for (int nn = 0; nn < BK; nn++) {
            const float4 a = *(const float4*)&As[nn][i*4];
            const float4 y = *(const float4*)&Ys[nn][j*4];
            float av[4] = {a.x, a.y, a.z, a.w};
            float yv[4] = {y.x, y.y, y.z, y.w};
#pragma unroll
            for (int c = 0; c < 4; c++)
#pragma unroll
                for (int b = 0; b < 4; b++) acc[c][b] = fmaf(av[c], yv[b], acc[c][b]);
        }
    }
#pragma unroll
    for (int b = 0; b < 4; b++) {
        int btv = bt0 + j*4 + b;
#pragma unroll
        for (int c = 0; c < 4; c++) {
            int m = m0 + i*4 + c;
            if (m < NN) Y2[(size_t)btv*NN + m] = fmaxf(acc[c][b], 0.f);
        }
    }
}

// ---------------- transpose W_ih [60,N] -> [N,64] ----------------
__global__ __launch_bounds__(256) void k_wih_t(const float* __restrict__ Wih, float* __restrict__ WihT) {
    int idx = blockIdx.x*256 + threadIdx.x;
    if (idx < NN*G4) {
        int n = idx / G4;
        int g = idx - n*G4;
        WihT[n*64 + g] = Wih[(size_t)g*NN + n];
    }
}

// ---------------- xW[bt,g] = sum_n Y2[bt,n]*W_ih[g,n] ----------------
__global__ __launch_bounds__(64) void k_xw(const float* __restrict__ Y2,
    const float* __restrict__ WihT, float* __restrict__ xW)
{
    int bt = blockIdx.x;
    int g = threadIdx.x;
    __shared__ __align__(16) float xsh[256];
    float acc = 0.f;
    for (int base = 0; base < NN; base += 256) {
        __syncthreads();
#pragma unroll
        for (int q = 0; q < 4; q++) {
            int n = base + q*64 + g;
            xsh[q*64 + g] = (n < NN) ? Y2[(size_t)bt*NN + n] : 0.f;
        }
        __syncthreads();
        int lim = min(256, NN - base);
#pragma unroll 4
        for (int nn = 0; nn < lim; nn++)
            acc = fmaf(xsh[nn], WihT[(base + nn)*64 + g], acc);
    }
    if (g < G4) xW[bt*64 + g] = acc;
}

// ---------------- LSTM recurrence (single block) + sigmoid(h_last) ----------------
__global__ __launch_bounds__(960) void k_lstm(const float* __restrict__ xW,
    const float* __restrict__ Whh, const float* __restrict__ bih, const float* __restrict__ bhh,
    const float* __restrict__ h0, const float* __restrict__ c0, float* __restrict__ s_out)
{
    __shared__ float h_s[BB][HH], c_s[BB][HH], g_s[BB][G4];
    __shared__ float whh_s[G4][HH];
    __shared__ float bsum[G4];
    int tid = threadIdx.x;
    if (tid < G4*HH) whh_s[tid/HH][tid%HH] = Whh[tid];
    if (tid < G4) bsum[tid] = bih[tid] + bhh[tid];
    if (tid < BB*HH) {
        h_s[tid/HH][tid%HH] = h0[tid];
        c_s[tid/HH][tid%HH] = c0[tid];
    }
    __syncthreads();
    int b  = tid / G4, jg = tid % G4;
    int b2 = tid / HH, k2 = tid % HH;
    for (int t = 0; t < TT; t++) {
        float v = xW[(b*TT + t)*64 + jg] + bsum[jg];
#pragma unroll
        for (int k = 0; k < HH; k++) v = fmaf(whh_s[jg][k], h_s[b][k], v);
        g_s[b][jg] = v;
        __syncthreads();
        if (tid < BB*HH) {
            float ig = sigmoidf(g_s[b2][k2]);
            float fg = sigmoidf(g_s[b2][HH + k2]);
            float gg = tanhf(g_s[b2][2*HH + k2]);
            float og = sigmoidf(g_s[b2][3*HH + k2]);
            float c = fg * c_s[b2][k2] + ig * gg;
            c_s[b2][k2] = c;
            h_s[b2][k2] = og * tanhf(c);
        }
        __syncthreads();
    }
    if (tid < BB*HH) s_out[tid] = sigmoidf(h_s[b2][k2]);
}

// ---------------- K FC heads ----------------
__global__ __launch_bounds__(256) void k_heads(const float* __restrict__ fc_w,
    const float* __restrict__ fc_b, const float* __restrict__ s, float* __restrict__ out)
{
    __shared__ float s_s[BB*HH];
    int tid = threadIdx.x;
    if (tid < BB*HH) s_s[tid] = s[tid];
    __syncthreads();
    int idx = blockIdx.x*256 + tid;
    if (idx >= KK*BB*NN) return;
    int k = idx / (BB*NN);
    int rem = idx - k*(BB*NN);
    int b = rem / NN;
    int n = rem - b*NN;
    const float* wp = fc_w + ((size_t)k*NN + n)*HH;
    const float* sp = s_s + b*HH;
    float v = fc_b[k*NN + n];
#pragma unroll
    for (int h = 0; h < HH; h++) v = fmaf(wp[h], sp[h], v);
    out[idx] = tanhf(v);
}

extern "C" void kernel_launch(void* const* d_in, const int* in_sizes, int n_in,
                              void* d_out, int out_size, void* d_ws, size_t ws_size,
                              hipStream_t stream) {
    const float* seq   = (const float*)d_in[0];
    const float* A     = (const float*)d_in[1];
    const float* W     = (const float*)d_in[2];
    const float* bias  = (const float*)d_in[3];
    const float* w2    = (const float*)d_in[4];
    const float* bias2 = (const float*)d_in[5];
    const float* Wih   = (const float*)d_in[6];
    const float* Whh   = (const float*)d_in[7];
    const float* bih   = (const float*)d_in[8];
    const float* bhh   = (const float*)d_in[9];
    const float* h0    = (const float*)d_in[10];
    const float* c0    = (const float*)d_in[11];
    const float* fcw   = (const float*)d_in[12];
    const float* fcb   = (const float*)d_in[13];
    float* ws = (float*)d_ws;
    float* rowsum = ws + OFS_ROWSUM;
    float* spad   = ws + OFS_SPAD;
    float* Y1     = ws + OFS_Y1;
    float* Y2     = ws + OFS_Y2;
    float* WihT   = ws + OFS_WIHT;
    float* xW     = ws + OFS_XW;
    float* s_sig  = ws + OFS_S;
    unsigned short* Abf = (unsigned short*)(ws + OFS_END_F);
    unsigned short* Wbf = Abf + ABF_ELEMS;
    float* out = (float*)d_out;

    hipLaunchKernelGGL(k_rowsum, dim3(NN), dim3(64), 0, stream, A, rowsum);
    hipLaunchKernelGGL(k_aprep, dim3((NKC*MFRAG*64 + 255)/256), dim3(256), 0, stream, A, Abf);
    hipLaunchKernelGGL(k_wprep, dim3((NKC*NCF*64 + 255)/256), dim3(256), 0, stream, W, Wbf);
    hipLaunchKernelGGL(k_sprep, dim3((BT*KPAD + 255)/256), dim3(256), 0, stream, seq, spad);
    hipLaunchKernelGGL(k_gcn1, dim3(NMT*BT), dim3(256), 0, stream, Abf, Wbf, spad, bias, w2, bias2, rowsum, Y1);
    hipLaunchKernelGGL(k_gcn2, dim3(21, 6), dim3(256), 0, stream, A, Y1, Y2);
    hipLaunchKernelGGL(k_wih_t, dim3((NN*G4 + 255)/256), dim3(256), 0, stream, Wih, WihT);
    hipLaunchKernelGGL(k_xw, dim3(BT), dim3(64), 0, stream, Y2, WihT, xW);
    hipLaunchKernelGGL(k_lstm, dim3(1), dim3(960), 0, stream, xW, Whh, bih, bhh, h0, c0, s_sig);
    hipLaunchKernelGGL(k_heads, dim3((KK*BB*NN + 255)/256), dim3(256), 0, stream, fcw, fcb, s_sig, out);
}

// Round 6
// 559.674 us; speedup vs baseline: 4.9846x; 1.4590x over previous
//
#include <hip/hip_runtime.h>
#include <hip/hip_bf16.h>
#include <math.h>

#define NN 1329
#define FF 130
#define BB 16
#define TT 24
#define HH 15
#define KK 5
#define BT (BB*TT)      // 384
#define G4 (4*HH)       // 60

// ---- MFMA gcn1 geometry ----
#define KPAD 1344
#define NKC 42          // k-chunks of 32
#define MFRAG 88        // row-frags of 16
#define NMT 11          // m-tiles of 128 rows
#define NCF 9           // col-frags of 16 (F=130 padded to 144)

// ---- gcn2 (fp32) geometry ----
#define BM 64
#define BK 32
#define SA 68
#define ZSPLIT 3        // k-split for gcn2

typedef __attribute__((ext_vector_type(8))) short short8v;   // 8 bf16
typedef __attribute__((ext_vector_type(4))) float f32x4;

// ---- workspace layout (float offsets) ----
#define OFS_ROWSUM 0
#define OFS_SPAD   1408
#define OFS_Y1     (OFS_SPAD + BT*KPAD)
#define OFS_Y2P    (OFS_Y1 + BT*NN)
#define OFS_WIHT   (OFS_Y2P + ZSPLIT*BT*NN)
#define OFS_XW     (OFS_WIHT + NN*64)
#define OFS_S      (OFS_XW + BT*64)
#define OFS_END_F  (OFS_S + 256)
#define ABF_ELEMS  (NKC*MFRAG*64*8)     // 1,892,352 ushorts
#define WBF_ELEMS  (NKC*NCF*64*8)       //   193,536 ushorts

__device__ __forceinline__ float sigmoidf(float x) { return 1.f / (1.f + expf(-x)); }

__device__ __forceinline__ unsigned short bf16rne(float x) {
    unsigned u = __float_as_uint(x);
    return (unsigned short)((u + 0x7fffu + ((u >> 16) & 1u)) >> 16);
}
__device__ __forceinline__ float bf16tof(unsigned short h) {
    return __uint_as_float(((unsigned)h) << 16);
}
// scale packed bf16 pair (dword) by two f32, repack to bf16 pair
__device__ __forceinline__ unsigned pk2(unsigned a, float sl, float sh) {
    float lo = __uint_as_float(a << 16) * sl;
    float hi = __uint_as_float(a & 0xffff0000u) * sh;
    return (unsigned)bf16rne(lo) | ((unsigned)bf16rne(hi) << 16);
}

__device__ __forceinline__ void gll16(const void* g, void* l) {
    __builtin_amdgcn_global_load_lds((const __attribute__((address_space(1))) unsigned*)g,
                                     (__attribute__((address_space(3))) unsigned*)l, 16, 0, 0);
}

// ================= fused prep (aprep | wprep | sprep | wihT | rowsum) =================
#define NB_APREP 924
#define NB_WPREP 95
#define NB_SPREP 2016
#define NB_WIHT  333
#define NB_ROWS  NN
#define NB_PREP  (NB_APREP+NB_WPREP+NB_SPREP+NB_WIHT+NB_ROWS)   // 4697

__global__ __launch_bounds__(256) void k_prep(
    const float* __restrict__ A, const float* __restrict__ W,
    const float* __restrict__ seq, const float* __restrict__ Wih,
    unsigned short* __restrict__ Abf, unsigned short* __restrict__ Wbf,
    float* __restrict__ spad, float* __restrict__ WihT, float* __restrict__ rowsum)
{
    __shared__ float r4[4];
    const int bid = blockIdx.x;
    const int tid = threadIdx.x;
    if (bid < NB_APREP) {
        // Abf[kcg][MF][l][j] = bf16(A[MF*16+(l&15)][kcg*32+(l>>4)*8+j])
        int s = bid*256 + tid;
        int l = s & 63;
        int t = s >> 6;
        int mf = t % MFRAG;
        int kcg = t / MFRAG;
        int m = mf*16 + (l & 15);
        int kb = kcg*32 + (l >> 4)*8;
        union { uint4 u4; unsigned short us[8]; } ow;
#pragma unroll
        for (int j = 0; j < 8; j++) {
            int k = kb + j;
            float x = (m < NN && k < NN) ? A[(size_t)m*NN + k] : 0.f;
            ow.us[j] = bf16rne(x);
        }
        *(uint4*)(Abf + (size_t)s*8) = ow.u4;
    } else if (bid < NB_APREP+NB_WPREP) {
        // Wbf[kcg][cf][l][j] = bf16(W[kcg*32+(l>>4)*8+j][cf*16+(l&15)])
        int s = (bid-NB_APREP)*256 + tid;
        if (s < NKC*NCF*64) {
            int l = s & 63;
            int t = s >> 6;
            int cf = t % NCF;
            int kcg = t / NCF;
            int f = cf*16 + (l & 15);
            int kb = kcg*32 + (l >> 4)*8;
            union { uint4 u4; unsigned short us[8]; } ow;
#pragma unroll
            for (int j = 0; j < 8; j++) {
                int k = kb + j;
                float x = (k < NN && f < FF) ? W[(size_t)k*FF + f] : 0.f;
                ow.us[j] = bf16rne(x);
            }
            *(uint4*)(Wbf + (size_t)s*8) = ow.u4;
        }
    } else if (bid < NB_APREP+NB_WPREP+NB_SPREP) {
        int idx = (bid-NB_APREP-NB_WPREP)*256 + tid;   // < BT*KPAD exactly
        int bt = idx / KPAD;
        int k  = idx - bt*KPAD;
        spad[idx] = (k < NN) ? seq[(size_t)bt*NN + k] : 0.f;
    } else if (bid < NB_APREP+NB_WPREP+NB_SPREP+NB_WIHT) {
        int idx = (bid-NB_APREP-NB_WPREP-NB_SPREP)*256 + tid;
        if (idx < NN*64) {
            int n = idx >> 6;
            int g = idx & 63;
            WihT[idx] = (g < G4) ? Wih[(size_t)g*NN + n] : 0.f;
        }
    } else {
        int m = bid - (NB_APREP+NB_WPREP+NB_SPREP+NB_WIHT);
        float a = 0.f;
        for (int n = tid; n < NN; n += 256) a += A[(size_t)m*NN + n];
#pragma unroll
        for (int off = 32; off; off >>= 1) a += __shfl_down(a, off, 64);
        if ((tid & 63) == 0) r4[tid >> 6] = a;
        __syncthreads();
        if (tid == 0) rowsum[m] = r4[0]+r4[1]+r4[2]+r4[3];
    }
}

// ============ fused GCN layer 1 (bf16 MFMA, 2-phase double-buffer) + w2 reduction ============
// Y1[bt,m] = sum_f relu( sum_k A[m,k]*s[bt,k]*W[k,f] + bias[f]*rowsum[m] ) * w2[f] + bias2
__global__ __launch_bounds__(256,2) void k_gcn1(
    const unsigned short* __restrict__ Abf, const unsigned short* __restrict__ Wbf,
    const float* __restrict__ spad,
    const float* __restrict__ bias, const float* __restrict__ w2, const float* __restrict__ bias2,
    const float* __restrict__ rowsum, float* __restrict__ Y1)
{
    __shared__ __align__(16) short Alds[2][8*64*8];     // 2 x 8 KB
    __shared__ __align__(16) short Blds[2][NCF*64*8];   // 2 x 9 KB

    const int id = blockIdx.x;
    const int mt = id / BT;          // bt varies fastest: concurrent blocks share A-panel
    const int bt = id - mt*BT;
    const int m0 = mt*128;
    const int tid = threadIdx.x;
    const int lane = tid & 63;
    const int wv = tid >> 6;
    const float* sb = spad + (size_t)bt*KPAD;

    f32x4 acc[2][NCF];
#pragma unroll
    for (int rf = 0; rf < 2; rf++)
#pragma unroll
        for (int cf = 0; cf < NCF; cf++) acc[rf][cf] = (f32x4){0.f, 0.f, 0.f, 0.f};

    // stage step kcg into buffer nb
    auto stageB = [&](int kcg, int nb) {
        const unsigned short* wsrc = Wbf + (size_t)kcg*(NCF*64*8);
#pragma unroll
        for (int it = 0; it < 2; ++it) {
            int slot = it*256 + tid;
            gll16(wsrc + (size_t)slot*8, &Blds[nb][slot*8]);
        }
        if (tid < 64) {
            int slot = 512 + tid;
            gll16(wsrc + (size_t)slot*8, &Blds[nb][slot*8]);
        }
    };
    auto stageA = [&](int kcg, int nb) {
#pragma unroll
        for (int it = 0; it < 2; ++it) {
            int s = it*256 + tid;
            int l = s & 63;
            int mf = s >> 6;
            uint4 ain = *(const uint4*)(Abf + ((size_t)(kcg*MFRAG + mt*8 + mf)*64 + l)*8);
            int kb = kcg*32 + (l >> 4)*8;
            float4 s0 = *(const float4*)(sb + kb);
            float4 s1 = *(const float4*)(sb + kb + 4);
            uint4 ow;
            ow.x = pk2(ain.x, s0.x, s0.y);
            ow.y = pk2(ain.y, s0.z, s0.w);
            ow.z = pk2(ain.z, s1.x, s1.y);
            ow.w = pk2(ain.w, s1.z, s1.w);
            *(uint4*)&Alds[nb][s*8] = ow;
        }
    };

    // prologue: fill buffer 0 with step 0
    stageB(0, 0);
    stageA(0, 0);
    __syncthreads();

    for (int t = 0; t < NKC; ++t) {
        const int cur = t & 1;
        // ds_read current fragments
        short8v bfr[NCF];
#pragma unroll
        for (int cf = 0; cf < NCF; cf++)
            bfr[cf] = *(const short8v*)&Blds[cur][(cf*64 + lane)*8];
        short8v a0 = *(const short8v*)&Alds[cur][((2*wv    )*64 + lane)*8];
        short8v a1 = *(const short8v*)&Alds[cur][((2*wv + 1)*64 + lane)*8];
        // stage next step while computing
        if (t + 1 < NKC) {
            stageB(t+1, cur^1);
            stageA(t+1, cur^1);
        }
        // MFMA
#pragma unroll
        for (int cf = 0; cf < NCF; cf++) {
            acc[0][cf] = __builtin_amdgcn_mfma_f32_16x16x32_bf16(a0, bfr[cf], acc[0][cf], 0, 0, 0);
            acc[1][cf] = __builtin_amdgcn_mfma_f32_16x16x32_bf16(a1, bfr[cf], acc[1][cf], 0, 0, 0);
        }
        __syncthreads();
    }

    // ---- epilogue: relu(X + bias*rowsum) dot w2, butterfly over 16 f-lanes ----
    const int fcol = lane & 15;
    const int rgrp = lane >> 4;
    float bv[NCF], wv2[NCF];
#pragma unroll
    for (int cf = 0; cf < NCF; cf++) {
        int f = cf*16 + fcol;
        bv[cf]  = (f < FF) ? bias[f] : 0.f;
        wv2[cf] = (f < FF) ? w2[f]   : 0.f;
    }
    float b2 = bias2[0];
#pragma unroll
    for (int rf = 0; rf < 2; rf++) {
#pragma unroll
        for (int r = 0; r < 4; r++) {
            int m = m0 + (2*wv + rf)*16 + rgrp*4 + r;
            float rs = (m < NN) ? rowsum[m] : 0.f;
            float p = 0.f;
#pragma unroll
            for (int cf = 0; cf < NCF; cf++)
                p += fmaxf(acc[rf][cf][r] + bv[cf]*rs, 0.f) * wv2[cf];
            p += __shfl_xor(p, 1, 64);
            p += __shfl_xor(p, 2, 64);
            p += __shfl_xor(p, 4, 64);
            p += __shfl_xor(p, 8, 64);
            if (fcol == 0 && m < NN) Y1[(size_t)bt*NN + m] = p + b2;
        }
    }
}

// ======= GCN layer 2 (split-K x3, partials): Y2p[z,bt,m] = sum_{n in z} A[m,n]*Y1[bt,n] =======
__global__ __launch_bounds__(256) void k_gcn2(const float* __restrict__ A,
    const float* __restrict__ Y1, float* __restrict__ Y2p)
{
    __shared__ __align__(16) float As[BK][SA];
    __shared__ __align__(16) float Ys[BK][SA];
    int mtile = blockIdx.x;
    int bt0 = blockIdx.y * 64;
    int z = blockIdx.z;
    int m0 = mtile * BM;
    const int tid = threadIdx.x;
    const int i = tid & 15;
    const int j = tid >> 4;
    const int nn_st = tid & 31;
    const int mg    = tid >> 5;

    float acc[4][4];
#pragma unroll
    for (int c = 0; c < 4; c++)
#pragma unroll
        for (int b = 0; b < 4; b++) acc[c][b] = 0.f;

    for (int s14 = 0; s14 < 14; ++s14) {
        int n0 = (z*14 + s14)*BK;
        __syncthreads();
        {
            int n = n0 + nn_st;
#pragma unroll
            for (int rr = 0; rr < 8; rr++) {
                int mm = rr*8 + mg;
                int m = m0 + mm;
                As[nn_st][mm] = (m < NN && n < NN) ? A[(size_t)m*NN + n] : 0.f;
                int bb = rr*8 + mg;
                Ys[nn_st][bb] = (n < NN) ? Y1[(size_t)(bt0 + bb)*NN + n] : 0.f;
            }
        }
        __syncthreads();
#pragma unroll 8
        for (int nn = 0; nn < BK; nn++) {
            const float4 a = *(const float4*)&As[nn][i*4];
            const float4 y = *(const float4*)&Ys[nn][j*4];
            float av[4] = {a.x, a.y, a.z, a.w};
            float yv[4] = {y.x, y.y, y.z, y.w};
#pragma unroll
            for (int c = 0; c < 4; c++)
#pragma unroll
                for (int b = 0; b < 4; b++) acc[c][b] = fmaf(av[c], yv[b], acc[c][b]);
        }
    }
#pragma unroll
    for (int b = 0; b < 4; b++) {
        int btv = bt0 + j*4 + b;
#pragma unroll
        for (int c = 0; c < 4; c++) {
            int m = m0 + i*4 + c;
            if (m < NN) Y2p[((size_t)z*BT + btv)*NN + m] = acc[c][b];
        }
    }
}

// ======= xW[bt,g] = sum_n relu(sum_z Y2p[z,bt,n]) * WihT[n,g] =======
__global__ __launch_bounds__(256) void k_xw(const float* __restrict__ Y2p,
    const float* __restrict__ WihT, float* __restrict__ xW)
{
    __shared__ float red[4][64];
    int bt = blockIdx.x;
    int tid = threadIdx.x;
    int p = tid >> 6, g = tid & 63;
    const float* y0 = Y2p + (size_t)bt*NN;
    const float* y1 = y0 + (size_t)BT*NN;
    const float* y2 = y1 + (size_t)BT*NN;
    float acc = 0.f;
    int nend = min((p+1)*336, NN);
    for (int n = p*336; n < nend; ++n) {
        float y = fmaxf(y0[n] + y1[n] + y2[n], 0.f);
        acc = fmaf(y, WihT[n*64 + g], acc);
    }
    red[p][g] = acc;
    __syncthreads();
    if (tid < 64) {
        float v = red[0][tid] + red[1][tid] + red[2][tid] + red[3][tid];
        if (tid < G4) xW[bt*64 + tid] = v;
    }
}

// ======= LSTM: one wave per batch element =======
__global__ __launch_bounds__(64) void k_lstm(const float* __restrict__ xW,
    const float* __restrict__ Whh, const float* __restrict__ bih, const float* __restrict__ bhh,
    const float* __restrict__ h0, const float* __restrict__ c0, float* __restrict__ s_out)
{
    __shared__ float h_s[16];
    int b = blockIdx.x;
    int lane = threadIdx.x;
    float whh_r[HH];
    float bs = 0.f;
    if (lane < G4) {
        bs = bih[lane] + bhh[lane];
#pragma unroll
        for (int k = 0; k < HH; k++) whh_r[k] = Whh[lane*HH + k];
    }
    float c_r = 0.f, h_last = 0.f;
    if (lane < HH) { h_s[lane] = h0[b*HH + lane]; c_r = c0[b*HH + lane]; }
    __syncthreads();
    for (int t = 0; t < TT; ++t) {
        float v = 0.f;
        if (lane < G4) {
            v = xW[(size_t)(b*TT + t)*64 + lane] + bs;
#pragma unroll
            for (int k = 0; k < HH; k++) v = fmaf(whh_r[k], h_s[k], v);
        }
        float vi = __shfl(v, lane, 64);
        float vf = __shfl(v, HH   + lane, 64);
        float vg = __shfl(v, 2*HH + lane, 64);
        float vo = __shfl(v, 3*HH + lane, 64);
        __syncthreads();
        if (lane < HH) {
            float c = sigmoidf(vf)*c_r + sigmoidf(vi)*tanhf(vg);
            c_r = c;
            float h = sigmoidf(vo)*tanhf(c);
            h_s[lane] = h;
            h_last = h;
        }
        __syncthreads();
    }
    if (lane < HH) s_out[b*HH + lane] = sigmoidf(h_last);
}

// ======= K FC heads: out[k,b,n] = tanh(fc_w[k,n,:]·s[b,:] + fc_b[k,n]) =======
__global__ __launch_bounds__(256) void k_heads(const float* __restrict__ fc_w,
    const float* __restrict__ fc_b, const float* __restrict__ s, float* __restrict__ out)
{
    __shared__ float s_s[BB*HH];
    int tid = threadIdx.x;
    if (tid < BB*HH) s_s[tid] = s[tid];
    __syncthreads();
    int idx = blockIdx.x*256 + tid;
    if (idx >= KK*BB*NN) return;
    int k = idx / (BB*NN);
    int rem = idx - k*(BB*NN);
    int b = rem / NN;
    int n = rem - b*NN;
    const float* wp = fc_w + ((size_t)k*NN + n)*HH;
    const float* sp = s_s + b*HH;
    float v = fc_b[k*NN + n];
#pragma unroll
    for (int h = 0; h < HH; h++) v = fmaf(wp[h], sp[h], v);
    out[idx] = tanhf(v);
}

extern "C" void kernel_launch(void* const* d_in, const int* in_sizes, int n_in,
                              void* d_out, int out_size, void* d_ws, size_t ws_size,
                              hipStream_t stream) {
    const float* seq   = (const float*)d_in[0];
    const float* A     = (const float*)d_in[1];
    const float* W     = (const float*)d_in[2];
    const float* bias  = (const float*)d_in[3];
    const float* w2    = (const float*)d_in[4];
    const float* bias2 = (const float*)d_in[5];
    const float* Wih   = (const float*)d_in[6];
    const float* Whh   = (const float*)d_in[7];
    const float* bih   = (const float*)d_in[8];
    const float* bhh   = (const float*)d_in[9];
    const float* h0    = (const float*)d_in[10];
    const float* c0    = (const float*)d_in[11];
    const float* fcw   = (const float*)d_in[12];
    const float* fcb   = (const float*)d_in[13];
    float* ws = (float*)d_ws;
    float* rowsum = ws + OFS_ROWSUM;
    float* spad   = ws + OFS_SPAD;
    float* Y1     = ws + OFS_Y1;
    float* Y2p    = ws + OFS_Y2P;
    float* WihT   = ws + OFS_WIHT;
    float* xW     = ws + OFS_XW;
    float* s_sig  = ws + OFS_S;
    unsigned short* Abf = (unsigned short*)(ws + OFS_END_F);
    unsigned short* Wbf = Abf + ABF_ELEMS;
    float* out = (float*)d_out;

    hipLaunchKernelGGL(k_prep, dim3(NB_PREP), dim3(256), 0, stream,
                       A, W, seq, Wih, Abf, Wbf, spad, WihT, rowsum);
    hipLaunchKernelGGL(k_gcn1, dim3(NMT*BT), dim3(256), 0, stream,
                       Abf, Wbf, spad, bias, w2, bias2, rowsum, Y1);
    hipLaunchKernelGGL(k_gcn2, dim3(21, 6, ZSPLIT), dim3(256), 0, stream, A, Y1, Y2p);
    hipLaunchKernelGGL(k_xw, dim3(BT), dim3(256), 0, stream, Y2p, WihT, xW);
    hipLaunchKernelGGL(k_lstm, dim3(BB), dim3(64), 0, stream, xW, Whh, bih, bhh, h0, c0, s_sig);
    hipLaunchKernelGGL(k_heads, dim3((KK*BB*NN + 255)/256), dim3(256), 0, stream, fcw, fcb, s_sig, out);
}

// Round 7
// 451.752 us; speedup vs baseline: 6.1754x; 1.2389x over previous
//
#include <hip/hip_runtime.h>
#include <hip/hip_bf16.h>
#include <math.h>

#define NN 1329
#define FF 130
#define BB 16
#define TT 24
#define HH 15
#define KK 5
#define BT (BB*TT)      // 384
#define G4 (4*HH)       // 60

// ---- MFMA geometry ----
#define KPAD 1344
#define NKC 42          // k-chunks of 32
#define MFRAG 88        // row-frags of 16
#define NMT 11          // m-tiles of 128 rows
#define NCF 9           // col-frags of 16 (F=130 padded to 144)
#define NBTF 24         // bt-frags of 16 (384/16)
#define ZSPLIT 7        // split-K for gcn2: 7 x 6 kc

typedef __attribute__((ext_vector_type(8))) short short8v;   // 8 bf16
typedef __attribute__((ext_vector_type(4))) float f32x4;

// ---- workspace layout (float offsets) ----
#define OFS_ROWSUM 0
#define OFS_SPAD   1408
#define OFS_Y1     (OFS_SPAD + BT*KPAD)
#define OFS_Y2P    (OFS_Y1 + BT*NN)
#define OFS_WIHT   (OFS_Y2P + ZSPLIT*BT*NN)
#define OFS_XW     (OFS_WIHT + NN*64)
#define OFS_S      (OFS_XW + BT*64)
#define OFS_END_F  (OFS_S + 256)
#define ABF_ELEMS  (NKC*MFRAG*64*8)     // 1,892,352 ushorts
#define WBF_ELEMS  (NKC*NCF*64*8)       //   193,536 ushorts
#define Y1BF_ELEMS (NKC*NBTF*64*8)      //   516,096 ushorts

__device__ __forceinline__ float sigmoidf(float x) { return 1.f / (1.f + expf(-x)); }

__device__ __forceinline__ unsigned short bf16rne(float x) {
    unsigned u = __float_as_uint(x);
    return (unsigned short)((u + 0x7fffu + ((u >> 16) & 1u)) >> 16);
}
__device__ __forceinline__ float bf16lo(unsigned a) { return __uint_as_float(a << 16); }
__device__ __forceinline__ float bf16hi(unsigned a) { return __uint_as_float(a & 0xffff0000u); }
// hardware packed f32->bf16 (RNE), 1 instr per pair
__device__ __forceinline__ unsigned cvtpk2(float lo, float hi) {
    unsigned r;
    asm volatile("v_cvt_pk_bf16_f32 %0, %1, %2" : "=v"(r) : "v"(lo), "v"(hi));
    return r;
}

__device__ __forceinline__ void gll16(const void* g, void* l) {
    __builtin_amdgcn_global_load_lds((const __attribute__((address_space(1))) unsigned*)g,
                                     (__attribute__((address_space(3))) unsigned*)l, 16, 0, 0);
}

// ================= fused prep (aprep | wprep | sprep | wihT | rowsum) =================
#define NB_APREP 924
#define NB_WPREP 95
#define NB_SPREP 2016
#define NB_WIHT  333
#define NB_ROWS  NN
#define NB_PREP  (NB_APREP+NB_WPREP+NB_SPREP+NB_WIHT+NB_ROWS)

__global__ __launch_bounds__(256) void k_prep(
    const float* __restrict__ A, const float* __restrict__ W,
    const float* __restrict__ seq, const float* __restrict__ Wih,
    unsigned short* __restrict__ Abf, unsigned short* __restrict__ Wbf,
    float* __restrict__ spad, float* __restrict__ WihT, float* __restrict__ rowsum)
{
    __shared__ float r4[4];
    const int bid = blockIdx.x;
    const int tid = threadIdx.x;
    if (bid < NB_APREP) {
        // Abf[kcg][MF][l][j] = bf16(A[MF*16+(l&15)][kcg*32+(l>>4)*8+j])
        int s = bid*256 + tid;
        int l = s & 63;
        int t = s >> 6;
        int mf = t % MFRAG;
        int kcg = t / MFRAG;
        int m = mf*16 + (l & 15);
        int kb = kcg*32 + (l >> 4)*8;
        union { uint4 u4; unsigned short us[8]; } ow;
#pragma unroll
        for (int j = 0; j < 8; j++) {
            int k = kb + j;
            float x = (m < NN && k < NN) ? A[(size_t)m*NN + k] : 0.f;
            ow.us[j] = bf16rne(x);
        }
        *(uint4*)(Abf + (size_t)s*8) = ow.u4;
    } else if (bid < NB_APREP+NB_WPREP) {
        // Wbf[kcg][cf][l][j] = bf16(W[kcg*32+(l>>4)*8+j][cf*16+(l&15)])
        int s = (bid-NB_APREP)*256 + tid;
        if (s < NKC*NCF*64) {
            int l = s & 63;
            int t = s >> 6;
            int cf = t % NCF;
            int kcg = t / NCF;
            int f = cf*16 + (l & 15);
            int kb = kcg*32 + (l >> 4)*8;
            union { uint4 u4; unsigned short us[8]; } ow;
#pragma unroll
            for (int j = 0; j < 8; j++) {
                int k = kb + j;
                float x = (k < NN && f < FF) ? W[(size_t)k*FF + f] : 0.f;
                ow.us[j] = bf16rne(x);
            }
            *(uint4*)(Wbf + (size_t)s*8) = ow.u4;
        }
    } else if (bid < NB_APREP+NB_WPREP+NB_SPREP) {
        int idx = (bid-NB_APREP-NB_WPREP)*256 + tid;   // < BT*KPAD exactly
        int bt = idx / KPAD;
        int k  = idx - bt*KPAD;
        spad[idx] = (k < NN) ? seq[(size_t)bt*NN + k] : 0.f;
    } else if (bid < NB_APREP+NB_WPREP+NB_SPREP+NB_WIHT) {
        int idx = (bid-NB_APREP-NB_WPREP-NB_SPREP)*256 + tid;
        if (idx < NN*64) {
            int n = idx >> 6;
            int g = idx & 63;
            WihT[idx] = (g < G4) ? Wih[(size_t)g*NN + n] : 0.f;
        }
    } else {
        int m = bid - (NB_APREP+NB_WPREP+NB_SPREP+NB_WIHT);
        float a = 0.f;
        for (int n = tid; n < NN; n += 256) a += A[(size_t)m*NN + n];
#pragma unroll
        for (int off = 32; off; off >>= 1) a += __shfl_down(a, off, 64);
        if ((tid & 63) == 0) r4[tid >> 6] = a;
        __syncthreads();
        if (tid == 0) rowsum[m] = r4[0]+r4[1]+r4[2]+r4[3];
    }
}

// ============ GCN layer 1: bf16 MFMA, A-frags direct to regs, B dbuf in LDS ============
// Y1[bt,m] = sum_f relu( sum_k A[m,k]*s[bt,k]*W[k,f] + bias[f]*rowsum[m] ) * w2[f] + bias2
__global__ __launch_bounds__(256,2) void k_gcn1(
    const unsigned short* __restrict__ Abf, const unsigned short* __restrict__ Wbf,
    const float* __restrict__ spad,
    const float* __restrict__ bias, const float* __restrict__ w2, const float* __restrict__ bias2,
    const float* __restrict__ rowsum, float* __restrict__ Y1)
{
    __shared__ __align__(16) short Blds[2][NCF*64*8];   // 2 x 9 KB

    const int id = blockIdx.x;
    const int mt = id / BT;          // bt fastest: concurrent blocks share A-panel
    const int bt = id - mt*BT;
    const int m0 = mt*128;
    const int tid = threadIdx.x;
    const int lane = tid & 63;
    const int wv = tid >> 6;
    const float* sb = spad + (size_t)bt*KPAD;
    const int klane = (lane >> 4)*8;

    f32x4 acc[2][NCF];
#pragma unroll
    for (int rf = 0; rf < 2; rf++)
#pragma unroll
        for (int cf = 0; cf < NCF; cf++) acc[rf][cf] = (f32x4){0.f, 0.f, 0.f, 0.f};

    auto stageB = [&](int kcg, int nb) {
        const unsigned short* wsrc = Wbf + (size_t)kcg*(NCF*64*8);
#pragma unroll
        for (int it = 0; it < 2; ++it) {
            int slot = it*256 + tid;
            gll16(wsrc + (size_t)slot*8, &Blds[nb][slot*8]);
        }
        if (tid < 64) {
            int slot = 512 + tid;
            gll16(wsrc + (size_t)slot*8, &Blds[nb][slot*8]);
        }
    };
    uint4 r0, r1; float4 s0, s1;
    auto loadA = [&](int kcg) {
        const unsigned short* p = Abf + ((size_t)(kcg*MFRAG + mt*8 + 2*wv)*64 + lane)*8;
        r0 = *(const uint4*)p;
        r1 = *(const uint4*)(p + 64*8);
        const float* sp = sb + kcg*32 + klane;
        s0 = *(const float4*)sp;
        s1 = *(const float4*)(sp + 4);
    };
    auto scaleA = [&](uint4 r) -> short8v {
        union { uint4 u4; short8v s8; } o;
        o.u4.x = cvtpk2(bf16lo(r.x)*s0.x, bf16hi(r.x)*s0.y);
        o.u4.y = cvtpk2(bf16lo(r.y)*s0.z, bf16hi(r.y)*s0.w);
        o.u4.z = cvtpk2(bf16lo(r.z)*s1.x, bf16hi(r.z)*s1.y);
        o.u4.w = cvtpk2(bf16lo(r.w)*s1.z, bf16hi(r.w)*s1.w);
        return o.s8;
    };

    // prologue
    stageB(0, 0);
    loadA(0);
    __syncthreads();
    short8v a0 = scaleA(r0), a1 = scaleA(r1);

    for (int t = 0; t < NKC; ++t) {
        const int cur = t & 1;
        if (t + 1 < NKC) { stageB(t+1, cur^1); loadA(t+1); }
        short8v bfr[NCF];
#pragma unroll
        for (int cf = 0; cf < NCF; cf++)
            bfr[cf] = *(const short8v*)&Blds[cur][(cf*64 + lane)*8];
#pragma unroll
        for (int cf = 0; cf < NCF; cf++) {
            acc[0][cf] = __builtin_amdgcn_mfma_f32_16x16x32_bf16(a0, bfr[cf], acc[0][cf], 0, 0, 0);
            acc[1][cf] = __builtin_amdgcn_mfma_f32_16x16x32_bf16(a1, bfr[cf], acc[1][cf], 0, 0, 0);
        }
        if (t + 1 < NKC) { a0 = scaleA(r0); a1 = scaleA(r1); }
        __syncthreads();
    }

    // ---- epilogue: relu(X + bias*rowsum) dot w2, butterfly over 16 f-lanes ----
    const int fcol = lane & 15;
    const int rgrp = lane >> 4;
    float bv[NCF], wv2[NCF];
#pragma unroll
    for (int cf = 0; cf < NCF; cf++) {
        int f = cf*16 + fcol;
        bv[cf]  = (f < FF) ? bias[f] : 0.f;
        wv2[cf] = (f < FF) ? w2[f]   : 0.f;
    }
    float b2 = bias2[0];
#pragma unroll
    for (int rf = 0; rf < 2; rf++) {
#pragma unroll
        for (int r = 0; r < 4; r++) {
            int m = m0 + (2*wv + rf)*16 + rgrp*4 + r;
            float rs = (m < NN) ? rowsum[m] : 0.f;
            float p = 0.f;
#pragma unroll
            for (int cf = 0; cf < NCF; cf++)
                p += fmaxf(acc[rf][cf][r] + bv[cf]*rs, 0.f) * wv2[cf];
            p += __shfl_xor(p, 1, 64);
            p += __shfl_xor(p, 2, 64);
            p += __shfl_xor(p, 4, 64);
            p += __shfl_xor(p, 8, 64);
            if (fcol == 0 && m < NN) Y1[(size_t)bt*NN + m] = p + b2;
        }
    }
}

// ======= Y1 -> bf16 B-fragment layout: Y1bf[kcg][btf][l][j] = Y1[btf*16+(l&15)][kcg*32+(l>>4)*8+j] =======
__global__ __launch_bounds__(256) void k_y1bf(const float* __restrict__ Y1, unsigned short* __restrict__ Y1bf) {
    int s = blockIdx.x*256 + threadIdx.x;    // < NKC*NBTF*64 exactly (252 blocks)
    int l = s & 63;
    int t = s >> 6;
    int btf = t % NBTF;
    int kcg = t / NBTF;
    int bt = btf*16 + (l & 15);
    int nb = kcg*32 + (l >> 4)*8;
    const float* yp = Y1 + (size_t)bt*NN;
    union { uint4 u4; unsigned short us[8]; } ow;
#pragma unroll
    for (int j = 0; j < 8; j++) {
        int n = nb + j;
        ow.us[j] = bf16rne((n < NN) ? yp[n] : 0.f);
    }
    *(uint4*)(Y1bf + (size_t)s*8) = ow.u4;
}

// ======= GCN layer 2: bf16 MFMA, no LDS, split-K; Y2p[z][m][bt] partials =======
__global__ __launch_bounds__(256) void k_gcn2(
    const unsigned short* __restrict__ Abf, const unsigned short* __restrict__ Y1bf,
    float* __restrict__ Y2p)
{
    const int mt = blockIdx.x;      // 11
    const int btg = blockIdx.y;     // 6 (64 bt each)
    const int z = blockIdx.z;       // 7 (6 kc each)
    const int tid = threadIdx.x;
    const int lane = tid & 63;
    const int wv = tid >> 6;

    f32x4 acc[2][4];
#pragma unroll
    for (int rf = 0; rf < 2; rf++)
#pragma unroll
        for (int cf = 0; cf < 4; cf++) acc[rf][cf] = (f32x4){0.f, 0.f, 0.f, 0.f};

#pragma unroll
    for (int kk = 0; kk < 6; ++kk) {
        int kcg = z*6 + kk;
        const unsigned short* ap = Abf + ((size_t)(kcg*MFRAG + mt*8 + 2*wv)*64 + lane)*8;
        short8v a0 = *(const short8v*)ap;
        short8v a1 = *(const short8v*)(ap + 64*8);
#pragma unroll
        for (int cf = 0; cf < 4; cf++) {
            const unsigned short* bp = Y1bf + ((size_t)((kcg*NBTF + btg*4 + cf)*64) + lane)*8;
            short8v b = *(const short8v*)bp;
            acc[0][cf] = __builtin_amdgcn_mfma_f32_16x16x32_bf16(a0, b, acc[0][cf], 0, 0, 0);
            acc[1][cf] = __builtin_amdgcn_mfma_f32_16x16x32_bf16(a1, b, acc[1][cf], 0, 0, 0);
        }
    }
#pragma unroll
    for (int rf = 0; rf < 2; rf++)
#pragma unroll
        for (int cf = 0; cf < 4; cf++)
#pragma unroll
            for (int r = 0; r < 4; r++) {
                int m = mt*128 + (2*wv + rf)*16 + (lane >> 4)*4 + r;
                int btv = btg*64 + cf*16 + (lane & 15);
                if (m < NN) Y2p[((size_t)z*NN + m)*BT + btv] = acc[rf][cf][r];
            }
}

// ======= xW[bt,g] = sum_n relu(sum_z Y2p[z,n,bt]) * WihT[n,g] =======
__global__ __launch_bounds__(256) void k_xw(const float* __restrict__ Y2p,
    const float* __restrict__ WihT, float* __restrict__ xW)
{
    __shared__ float red[4][64];
    int bt = blockIdx.x;
    int tid = threadIdx.x;
    int p = tid >> 6, g = tid & 63;
    float acc = 0.f;
    int nend = min((p+1)*336, NN);
    for (int n = p*336; n < nend; ++n) {
        float y = 0.f;
#pragma unroll
        for (int z = 0; z < ZSPLIT; ++z)
            y += Y2p[((size_t)z*NN + n)*BT + bt];
        y = fmaxf(y, 0.f);
        acc = fmaf(y, WihT[n*64 + g], acc);
    }
    red[p][g] = acc;
    __syncthreads();
    if (tid < 64) {
        float v = red[0][tid] + red[1][tid] + red[2][tid] + red[3][tid];
        if (tid < G4) xW[bt*64 + tid] = v;
    }
}

// ======= LSTM: one wave per batch element =======
__global__ __launch_bounds__(64) void k_lstm(const float* __restrict__ xW,
    const float* __restrict__ Whh, const float* __restrict__ bih, const float* __restrict__ bhh,
    const float* __restrict__ h0, const float* __restrict__ c0, float* __restrict__ s_out)
{
    __shared__ float h_s[16];
    int b = blockIdx.x;
    int lane = threadIdx.x;
    float whh_r[HH];
    float bs = 0.f;
    if (lane < G4) {
        bs = bih[lane] + bhh[lane];
#pragma unroll
        for (int k = 0; k < HH; k++) whh_r[k] = Whh[lane*HH + k];
    }
    float c_r = 0.f, h_last = 0.f;
    if (lane < HH) { h_s[lane] = h0[b*HH + lane]; c_r = c0[b*HH + lane]; }
    __syncthreads();
    for (int t = 0; t < TT; ++t) {
        float v = 0.f;
        if (lane < G4) {
            v = xW[(size_t)(b*TT + t)*64 + lane] + bs;
#pragma unroll
            for (int k = 0; k < HH; k++) v = fmaf(whh_r[k], h_s[k], v);
        }
        float vi = __shfl(v, lane, 64);
        float vf = __shfl(v, HH   + lane, 64);
        float vg = __shfl(v, 2*HH + lane, 64);
        float vo = __shfl(v, 3*HH + lane, 64);
        __syncthreads();
        if (lane < HH) {
            float c = sigmoidf(vf)*c_r + sigmoidf(vi)*tanhf(vg);
            c_r = c;
            float h = sigmoidf(vo)*tanhf(c);
            h_s[lane] = h;
            h_last = h;
        }
        __syncthreads();
    }
    if (lane < HH) s_out[b*HH + lane] = sigmoidf(h_last);
}

// ======= K FC heads: out[k,b,n] = tanh(fc_w[k,n,:]·s[b,:] + fc_b[k,n]) =======
__global__ __launch_bounds__(256) void k_heads(const float* __restrict__ fc_w,
    const float* __restrict__ fc_b, const float* __restrict__ s, float* __restrict__ out)
{
    __shared__ float s_s[BB*HH];
    int tid = threadIdx.x;
    if (tid < BB*HH) s_s[tid] = s[tid];
    __syncthreads();
    int idx = blockIdx.x*256 + tid;
    if (idx >= KK*BB*NN) return;
    int k = idx / (BB*NN);
    int rem = idx - k*(BB*NN);
    int b = rem / NN;
    int n = rem - b*NN;
    const float* wp = fc_w + ((size_t)k*NN + n)*HH;
    const float* sp = s_s + b*HH;
    float v = fc_b[k*NN + n];
#pragma unroll
    for (int h = 0; h < HH; h++) v = fmaf(wp[h], sp[h], v);
    out[idx] = tanhf(v);
}

extern "C" void kernel_launch(void* const* d_in, const int* in_sizes, int n_in,
                              void* d_out, int out_size, void* d_ws, size_t ws_size,
                              hipStream_t stream) {
    const float* seq   = (const float*)d_in[0];
    const float* A     = (const float*)d_in[1];
    const float* W     = (const float*)d_in[2];
    const float* bias  = (const float*)d_in[3];
    const float* w2    = (const float*)d_in[4];
    const float* bias2 = (const float*)d_in[5];
    const float* Wih   = (const float*)d_in[6];
    const float* Whh   = (const float*)d_in[7];
    const float* bih   = (const float*)d_in[8];
    const float* bhh   = (const float*)d_in[9];
    const float* h0    = (const float*)d_in[10];
    const float* c0    = (const float*)d_in[11];
    const float* fcw   = (const float*)d_in[12];
    const float* fcb   = (const float*)d_in[13];
    float* ws = (float*)d_ws;
    float* rowsum = ws + OFS_ROWSUM;
    float* spad   = ws + OFS_SPAD;
    float* Y1     = ws + OFS_Y1;
    float* Y2p    = ws + OFS_Y2P;
    float* WihT   = ws + OFS_WIHT;
    float* xW     = ws + OFS_XW;
    float* s_sig  = ws + OFS_S;
    unsigned short* Abf  = (unsigned short*)(ws + OFS_END_F);
    unsigned short* Wbf  = Abf + ABF_ELEMS;
    unsigned short* Y1bf = Wbf + WBF_ELEMS;
    float* out = (float*)d_out;

    hipLaunchKernelGGL(k_prep, dim3(NB_PREP), dim3(256), 0, stream,
                       A, W, seq, Wih, Abf, Wbf, spad, WihT, rowsum);
    hipLaunchKernelGGL(k_gcn1, dim3(NMT*BT), dim3(256), 0, stream,
                       Abf, Wbf, spad, bias, w2, bias2, rowsum, Y1);
    hipLaunchKernelGGL(k_y1bf, dim3(NKC*NBTF*64/256), dim3(256), 0, stream, Y1, Y1bf);
    hipLaunchKernelGGL(k_gcn2, dim3(NMT, 6, ZSPLIT), dim3(256), 0, stream, Abf, Y1bf, Y2p);
    hipLaunchKernelGGL(k_xw, dim3(BT), dim3(256), 0, stream, Y2p, WihT, xW);
    hipLaunchKernelGGL(k_lstm, dim3(BB), dim3(64), 0, stream, xW, Whh, bih, bhh, h0, c0, s_sig);
    hipLaunchKernelGGL(k_heads, dim3((KK*BB*NN + 255)/256), dim3(256), 0, stream, fcw, fcb, s_sig, out);
}

// Round 8
// 367.593 us; speedup vs baseline: 7.5892x; 1.2289x over previous
//
#include <hip/hip_runtime.h>
#include <hip/hip_bf16.h>
#include <math.h>

#define NN 1329
#define FF 130
#define BB 16
#define TT 24
#define HH 15
#define KK 5
#define BT (BB*TT)      // 384
#define G4 (4*HH)       // 60

// ---- MFMA geometry ----
#define KPAD 1344
#define NKC 42          // k-chunks of 32
#define MFRAG 88        // row-frags of 16
#define NMT 11          // m-tiles of 128 rows
#define NCF 9           // col-frags of 16 (F=130 padded to 144)
#define NBTF 24         // bt-frags of 16 (384/16)
#define NKCO 44         // kcg slots for Y2A (11 mt * 4; slots 42,43 written, unread)

typedef __attribute__((ext_vector_type(8))) short short8v;   // 8 bf16
typedef __attribute__((ext_vector_type(4))) float f32x4;

// ---- workspace layout (float offsets) ----
#define OFS_ROWSUM 0
#define OFS_SPAD   1408
#define OFS_Y1     (OFS_SPAD + BT*KPAD)
#define OFS_XW     (OFS_Y1 + BT*NN)
#define OFS_S      (OFS_XW + BT*64)
#define OFS_END_F  (OFS_S + 256)
#define ABF_ELEMS  (NKC*MFRAG*64*8)     // 1,892,352 ushorts
#define WBF_ELEMS  (NKC*NCF*64*8)       //   193,536 ushorts
#define WTB_ELEMS  (NKC*4*64*8)         //    86,016 ushorts
#define Y2A_ELEMS  (NKCO*NBTF*64*8)     //   540,672 ushorts

__device__ __forceinline__ float sigmoidf(float x) { return 1.f / (1.f + expf(-x)); }

__device__ __forceinline__ unsigned short bf16rne(float x) {
    unsigned u = __float_as_uint(x);
    return (unsigned short)((u + 0x7fffu + ((u >> 16) & 1u)) >> 16);
}
__device__ __forceinline__ float bf16lo(unsigned a) { return __uint_as_float(a << 16); }
__device__ __forceinline__ float bf16hi(unsigned a) { return __uint_as_float(a & 0xffff0000u); }
// hardware packed f32->bf16 (RNE), 1 instr per pair
__device__ __forceinline__ unsigned cvtpk2(float lo, float hi) {
    unsigned r;
    asm volatile("v_cvt_pk_bf16_f32 %0, %1, %2" : "=v"(r) : "v"(lo), "v"(hi));
    return r;
}

__device__ __forceinline__ void gll16(const void* g, void* l) {
    __builtin_amdgcn_global_load_lds((const __attribute__((address_space(1))) unsigned*)g,
                                     (__attribute__((address_space(3))) unsigned*)l, 16, 0, 0);
}

// ================= fused prep (aprep | wprep | sprep | wihTbf | rowsum) =================
#define NB_APREP 924
#define NB_WPREP 95
#define NB_SPREP 2016
#define NB_WTB   42
#define NB_ROWS  NN
#define NB_PREP  (NB_APREP+NB_WPREP+NB_SPREP+NB_WTB+NB_ROWS)   // 4406

__global__ __launch_bounds__(256) void k_prep(
    const float* __restrict__ A, const float* __restrict__ W,
    const float* __restrict__ seq, const float* __restrict__ Wih,
    unsigned short* __restrict__ Abf, unsigned short* __restrict__ Wbf,
    float* __restrict__ spad, unsigned short* __restrict__ WihTbf, float* __restrict__ rowsum)
{
    __shared__ float r4[4];
    const int bid = blockIdx.x;
    const int tid = threadIdx.x;
    if (bid < NB_APREP) {
        // Abf[kcg][MF][l][j] = bf16(A[MF*16+(l&15)][kcg*32+(l>>4)*8+j])
        int s = bid*256 + tid;
        int l = s & 63;
        int t = s >> 6;
        int mf = t % MFRAG;
        int kcg = t / MFRAG;
        int m = mf*16 + (l & 15);
        int kb = kcg*32 + (l >> 4)*8;
        union { uint4 u4; unsigned short us[8]; } ow;
#pragma unroll
        for (int j = 0; j < 8; j++) {
            int k = kb + j;
            float x = (m < NN && k < NN) ? A[(size_t)m*NN + k] : 0.f;
            ow.us[j] = bf16rne(x);
        }
        *(uint4*)(Abf + (size_t)s*8) = ow.u4;
    } else if (bid < NB_APREP+NB_WPREP) {
        // Wbf[kcg][cf][l][j] = bf16(W[kcg*32+(l>>4)*8+j][cf*16+(l&15)])
        int s = (bid-NB_APREP)*256 + tid;
        if (s < NKC*NCF*64) {
            int l = s & 63;
            int t = s >> 6;
            int cf = t % NCF;
            int kcg = t / NCF;
            int f = cf*16 + (l & 15);
            int kb = kcg*32 + (l >> 4)*8;
            union { uint4 u4; unsigned short us[8]; } ow;
#pragma unroll
            for (int j = 0; j < 8; j++) {
                int k = kb + j;
                float x = (k < NN && f < FF) ? W[(size_t)k*FF + f] : 0.f;
                ow.us[j] = bf16rne(x);
            }
            *(uint4*)(Wbf + (size_t)s*8) = ow.u4;
        }
    } else if (bid < NB_APREP+NB_WPREP+NB_SPREP) {
        int idx = (bid-NB_APREP-NB_WPREP)*256 + tid;   // < BT*KPAD exactly
        int bt = idx / KPAD;
        int k  = idx - bt*KPAD;
        spad[idx] = (k < NN) ? seq[(size_t)bt*NN + k] : 0.f;
    } else if (bid < NB_APREP+NB_WPREP+NB_SPREP+NB_WTB) {
        // WihTbf[kcg][gf][l][j] = bf16(Wih[gf*16+(l&15)][kcg*32+(l>>4)*8+j]), zero-padded
        int s = (bid-NB_APREP-NB_WPREP-NB_SPREP)*256 + tid;   // < NKC*4*64 exactly
        int l = s & 63;
        int t = s >> 6;
        int gf = t & 3;
        int kcg = t >> 2;
        int g = gf*16 + (l & 15);
        int nb = kcg*32 + (l >> 4)*8;
        union { uint4 u4; unsigned short us[8]; } ow;
#pragma unroll
        for (int j = 0; j < 8; j++) {
            int n = nb + j;
            float x = (g < G4 && n < NN) ? Wih[(size_t)g*NN + n] : 0.f;
            ow.us[j] = bf16rne(x);
        }
        *(uint4*)(WihTbf + (size_t)s*8) = ow.u4;
    } else {
        int m = bid - (NB_APREP+NB_WPREP+NB_SPREP+NB_WTB);
        float a = 0.f;
        for (int n = tid; n < NN; n += 256) a += A[(size_t)m*NN + n];
#pragma unroll
        for (int off = 32; off; off >>= 1) a += __shfl_down(a, off, 64);
        if ((tid & 63) == 0) r4[tid >> 6] = a;
        __syncthreads();
        if (tid == 0) rowsum[m] = r4[0]+r4[1]+r4[2]+r4[3];
    }
}

// ============ GCN layer 1: bf16 MFMA, A-frags direct to regs, B dbuf in LDS ============
// (unchanged from R7: 217 us, MfmaUtil 44%)
__global__ __launch_bounds__(256,2) void k_gcn1(
    const unsigned short* __restrict__ Abf, const unsigned short* __restrict__ Wbf,
    const float* __restrict__ spad,
    const float* __restrict__ bias, const float* __restrict__ w2, const float* __restrict__ bias2,
    const float* __restrict__ rowsum, float* __restrict__ Y1)
{
    __shared__ __align__(16) short Blds[2][NCF*64*8];   // 2 x 9 KB

    const int id = blockIdx.x;
    const int mt = id / BT;
    const int bt = id - mt*BT;
    const int m0 = mt*128;
    const int tid = threadIdx.x;
    const int lane = tid & 63;
    const int wv = tid >> 6;
    const float* sb = spad + (size_t)bt*KPAD;
    const int klane = (lane >> 4)*8;

    f32x4 acc[2][NCF];
#pragma unroll
    for (int rf = 0; rf < 2; rf++)
#pragma unroll
        for (int cf = 0; cf < NCF; cf++) acc[rf][cf] = (f32x4){0.f, 0.f, 0.f, 0.f};

    auto stageB = [&](int kcg, int nb) {
        const unsigned short* wsrc = Wbf + (size_t)kcg*(NCF*64*8);
#pragma unroll
        for (int it = 0; it < 2; ++it) {
            int slot = it*256 + tid;
            gll16(wsrc + (size_t)slot*8, &Blds[nb][slot*8]);
        }
        if (tid < 64) {
            int slot = 512 + tid;
            gll16(wsrc + (size_t)slot*8, &Blds[nb][slot*8]);
        }
    };
    uint4 r0, r1; float4 s0, s1;
    auto loadA = [&](int kcg) {
        const unsigned short* p = Abf + ((size_t)(kcg*MFRAG + mt*8 + 2*wv)*64 + lane)*8;
        r0 = *(const uint4*)p;
        r1 = *(const uint4*)(p + 64*8);
        const float* sp = sb + kcg*32 + klane;
        s0 = *(const float4*)sp;
        s1 = *(const float4*)(sp + 4);
    };
    auto scaleA = [&](uint4 r) -> short8v {
        union { uint4 u4; short8v s8; } o;
        o.u4.x = cvtpk2(bf16lo(r.x)*s0.x, bf16hi(r.x)*s0.y);
        o.u4.y = cvtpk2(bf16lo(r.y)*s0.z, bf16hi(r.y)*s0.w);
        o.u4.z = cvtpk2(bf16lo(r.z)*s1.x, bf16hi(r.z)*s1.y);
        o.u4.w = cvtpk2(bf16lo(r.w)*s1.z, bf16hi(r.w)*s1.w);
        return o.s8;
    };

    stageB(0, 0);
    loadA(0);
    __syncthreads();
    short8v a0 = scaleA(r0), a1 = scaleA(r1);

    for (int t = 0; t < NKC; ++t) {
        const int cur = t & 1;
        if (t + 1 < NKC) { stageB(t+1, cur^1); loadA(t+1); }
        short8v bfr[NCF];
#pragma unroll
        for (int cf = 0; cf < NCF; cf++)
            bfr[cf] = *(const short8v*)&Blds[cur][(cf*64 + lane)*8];
#pragma unroll
        for (int cf = 0; cf < NCF; cf++) {
            acc[0][cf] = __builtin_amdgcn_mfma_f32_16x16x32_bf16(a0, bfr[cf], acc[0][cf], 0, 0, 0);
            acc[1][cf] = __builtin_amdgcn_mfma_f32_16x16x32_bf16(a1, bfr[cf], acc[1][cf], 0, 0, 0);
        }
        if (t + 1 < NKC) { a0 = scaleA(r0); a1 = scaleA(r1); }
        __syncthreads();
    }

    const int fcol = lane & 15;
    const int rgrp = lane >> 4;
    float bv[NCF], wv2[NCF];
#pragma unroll
    for (int cf = 0; cf < NCF; cf++) {
        int f = cf*16 + fcol;
        bv[cf]  = (f < FF) ? bias[f] : 0.f;
        wv2[cf] = (f < FF) ? w2[f]   : 0.f;
    }
    float b2 = bias2[0];
#pragma unroll
    for (int rf = 0; rf < 2; rf++) {
#pragma unroll
        for (int r = 0; r < 4; r++) {
            int m = m0 + (2*wv + rf)*16 + rgrp*4 + r;
            float rs = (m < NN) ? rowsum[m] : 0.f;
            float p = 0.f;
#pragma unroll
            for (int cf = 0; cf < NCF; cf++)
                p += fmaxf(acc[rf][cf][r] + bv[cf]*rs, 0.f) * wv2[cf];
            p += __shfl_xor(p, 1, 64);
            p += __shfl_xor(p, 2, 64);
            p += __shfl_xor(p, 4, 64);
            p += __shfl_xor(p, 8, 64);
            if (fcol == 0 && m < NN) Y1[(size_t)bt*NN + m] = p + b2;
        }
    }
}

// ======= GCN layer 2: full-K bf16 MFMA, B from fp32 Y1 inline; epilogue relu -> Y2A (A-frag bf16) =======
// Y2A[kcg][btf][l][j] = bf16(relu(Y2[btf*16+(l&15)][kcg*32+(l>>4)*8+j]))
__global__ __launch_bounds__(256) void k_gcn2(
    const unsigned short* __restrict__ Abf, const float* __restrict__ Y1,
    unsigned short* __restrict__ Y2A)
{
    const int mt  = blockIdx.x;     // 11
    const int btg = blockIdx.y;     // 12 (32 bt each)
    const int tid = threadIdx.x;
    const int lane = tid & 63;
    const int wv = tid >> 6;
    const int q = lane >> 4;

    f32x4 acc[2][2];
#pragma unroll
    for (int rf = 0; rf < 2; rf++)
#pragma unroll
        for (int cf = 0; cf < 2; cf++) acc[rf][cf] = (f32x4){0.f, 0.f, 0.f, 0.f};

    const float* y1r0 = Y1 + (size_t)((btg*2 + 0)*16 + (lane & 15))*NN;
    const float* y1r1 = Y1 + (size_t)((btg*2 + 1)*16 + (lane & 15))*NN;
    const int nq = q*8;

    for (int kcg = 0; kcg < NKC; ++kcg) {
        const unsigned short* ap = Abf + ((size_t)(kcg*MFRAG + mt*8 + 2*wv)*64 + lane)*8;
        short8v a0 = *(const short8v*)ap;
        short8v a1 = *(const short8v*)(ap + 64*8);
        int n0 = kcg*32 + nq;
        union { uint4 u4; short8v s8; } b0, b1;
        if (kcg < NKC-1) {
            float4 x0 = *(const float4*)(y1r0 + n0);
            float4 x1 = *(const float4*)(y1r0 + n0 + 4);
            b0.u4.x = cvtpk2(x0.x, x0.y); b0.u4.y = cvtpk2(x0.z, x0.w);
            b0.u4.z = cvtpk2(x1.x, x1.y); b0.u4.w = cvtpk2(x1.z, x1.w);
            float4 y0 = *(const float4*)(y1r1 + n0);
            float4 y1v = *(const float4*)(y1r1 + n0 + 4);
            b1.u4.x = cvtpk2(y0.x, y0.y); b1.u4.y = cvtpk2(y0.z, y0.w);
            b1.u4.z = cvtpk2(y1v.x, y1v.y); b1.u4.w = cvtpk2(y1v.z, y1v.w);
        } else {
            float xa[8], xb[8];
#pragma unroll
            for (int j = 0; j < 8; j++) {
                int n = n0 + j;
                xa[j] = (n < NN) ? y1r0[n] : 0.f;
                xb[j] = (n < NN) ? y1r1[n] : 0.f;
            }
            b0.u4.x = cvtpk2(xa[0], xa[1]); b0.u4.y = cvtpk2(xa[2], xa[3]);
            b0.u4.z = cvtpk2(xa[4], xa[5]); b0.u4.w = cvtpk2(xa[6], xa[7]);
            b1.u4.x = cvtpk2(xb[0], xb[1]); b1.u4.y = cvtpk2(xb[2], xb[3]);
            b1.u4.z = cvtpk2(xb[4], xb[5]); b1.u4.w = cvtpk2(xb[6], xb[7]);
        }
        acc[0][0] = __builtin_amdgcn_mfma_f32_16x16x32_bf16(a0, b0.s8, acc[0][0], 0, 0, 0);
        acc[1][0] = __builtin_amdgcn_mfma_f32_16x16x32_bf16(a1, b0.s8, acc[1][0], 0, 0, 0);
        acc[0][1] = __builtin_amdgcn_mfma_f32_16x16x32_bf16(a0, b1.s8, acc[0][1], 0, 0, 0);
        acc[1][1] = __builtin_amdgcn_mfma_f32_16x16x32_bf16(a1, b1.s8, acc[1][1], 0, 0, 0);
    }

    // epilogue: relu -> bf16 -> A-frag layout (derivation in commit notes)
    const int kcgo = mt*4 + wv;            // unique per (mt,wv); 42,43 written but unread
    const int jofs = (q & 1)*4;
#pragma unroll
    for (int rf = 0; rf < 2; rf++) {
        int lp = (rf*2 + (q >> 1))*16 + (lane & 15);
#pragma unroll
        for (int cf = 0; cf < 2; cf++) {
            int btf = btg*2 + cf;
            uint2 w2v;
            w2v.x = cvtpk2(fmaxf(acc[rf][cf][0], 0.f), fmaxf(acc[rf][cf][1], 0.f));
            w2v.y = cvtpk2(fmaxf(acc[rf][cf][2], 0.f), fmaxf(acc[rf][cf][3], 0.f));
            *(uint2*)(Y2A + ((size_t)(kcgo*NBTF + btf)*64 + lp)*8 + jofs) = w2v;
        }
    }
}

// ======= xW = relu(Y2) @ WihT via MFMA: [384 x 1344] x [1344 x 64] =======
__global__ __launch_bounds__(64) void k_xwm(
    const unsigned short* __restrict__ Y2A, const unsigned short* __restrict__ WihTbf,
    float* __restrict__ xW)
{
    const int btf = blockIdx.x;   // 24
    const int lane = threadIdx.x;
    f32x4 acc[4];
#pragma unroll
    for (int gf = 0; gf < 4; gf++) acc[gf] = (f32x4){0.f, 0.f, 0.f, 0.f};

    for (int kcg = 0; kcg < NKC; ++kcg) {
        short8v a = *(const short8v*)(Y2A + ((size_t)(kcg*NBTF + btf)*64 + lane)*8);
#pragma unroll
        for (int gf = 0; gf < 4; gf++) {
            short8v b = *(const short8v*)(WihTbf + ((size_t)(kcg*4 + gf)*64 + lane)*8);
            acc[gf] = __builtin_amdgcn_mfma_f32_16x16x32_bf16(a, b, acc[gf], 0, 0, 0);
        }
    }
#pragma unroll
    for (int gf = 0; gf < 4; gf++)
#pragma unroll
        for (int r = 0; r < 4; r++) {
            int bt = btf*16 + (lane >> 4)*4 + r;
            xW[(size_t)bt*64 + gf*16 + (lane & 15)] = acc[gf][r];
        }
}

// ======= LSTM: one wave per batch element =======
__global__ __launch_bounds__(64) void k_lstm(const float* __restrict__ xW,
    const float* __restrict__ Whh, const float* __restrict__ bih, const float* __restrict__ bhh,
    const float* __restrict__ h0, const float* __restrict__ c0, float* __restrict__ s_out)
{
    __shared__ float h_s[16];
    int b = blockIdx.x;
    int lane = threadIdx.x;
    float whh_r[HH];
    float bs = 0.f;
    if (lane < G4) {
        bs = bih[lane] + bhh[lane];
#pragma unroll
        for (int k = 0; k < HH; k++) whh_r[k] = Whh[lane*HH + k];
    }
    float c_r = 0.f, h_last = 0.f;
    if (lane < HH) { h_s[lane] = h0[b*HH + lane]; c_r = c0[b*HH + lane]; }
    __syncthreads();
    for (int t = 0; t < TT; ++t) {
        float v = 0.f;
        if (lane < G4) {
            v = xW[(size_t)(b*TT + t)*64 + lane] + bs;
#pragma unroll
            for (int k = 0; k < HH; k++) v = fmaf(whh_r[k], h_s[k], v);
        }
        float vi = __shfl(v, lane, 64);
        float vf = __shfl(v, HH   + lane, 64);
        float vg = __shfl(v, 2*HH + lane, 64);
        float vo = __shfl(v, 3*HH + lane, 64);
        __syncthreads();
        if (lane < HH) {
            float c = sigmoidf(vf)*c_r + sigmoidf(vi)*tanhf(vg);
            c_r = c;
            float h = sigmoidf(vo)*tanhf(c);
            h_s[lane] = h;
            h_last = h;
        }
        __syncthreads();
    }
    if (lane < HH) s_out[b*HH + lane] = sigmoidf(h_last);
}

// ======= K FC heads: out[k,b,n] = tanh(fc_w[k,n,:]·s[b,:] + fc_b[k,n]) =======
__global__ __launch_bounds__(256) void k_heads(const float* __restrict__ fc_w,
    const float* __restrict__ fc_b, const float* __restrict__ s, float* __restrict__ out)
{
    __shared__ float s_s[BB*HH];
    int tid = threadIdx.x;
    if (tid < BB*HH) s_s[tid] = s[tid];
    __syncthreads();
    int idx = blockIdx.x*256 + tid;
    if (idx >= KK*BB*NN) return;
    int k = idx / (BB*NN);
    int rem = idx - k*(BB*NN);
    int b = rem / NN;
    int n = rem - b*NN;
    const float* wp = fc_w + ((size_t)k*NN + n)*HH;
    const float* sp = s_s + b*HH;
    float v = fc_b[k*NN + n];
#pragma unroll
    for (int h = 0; h < HH; h++) v = fmaf(wp[h], sp[h], v);
    out[idx] = tanhf(v);
}

extern "C" void kernel_launch(void* const* d_in, const int* in_sizes, int n_in,
                              void* d_out, int out_size, void* d_ws, size_t ws_size,
                              hipStream_t stream) {
    const float* seq   = (const float*)d_in[0];
    const float* A     = (const float*)d_in[1];
    const float* W     = (const float*)d_in[2];
    const float* bias  = (const float*)d_in[3];
    const float* w2    = (const float*)d_in[4];
    const float* bias2 = (const float*)d_in[5];
    const float* Wih   = (const float*)d_in[6];
    const float* Whh   = (const float*)d_in[7];
    const float* bih   = (const float*)d_in[8];
    const float* bhh   = (const float*)d_in[9];
    const float* h0    = (const float*)d_in[10];
    const float* c0    = (const float*)d_in[11];
    const float* fcw   = (const float*)d_in[12];
    const float* fcb   = (const float*)d_in[13];
    float* ws = (float*)d_ws;
    float* rowsum = ws + OFS_ROWSUM;
    float* spad   = ws + OFS_SPAD;
    float* Y1     = ws + OFS_Y1;
    float* xW     = ws + OFS_XW;
    float* s_sig  = ws + OFS_S;
    unsigned short* Abf    = (unsigned short*)(ws + OFS_END_F);
    unsigned short* Wbf    = Abf + ABF_ELEMS;
    unsigned short* WihTbf = Wbf + WBF_ELEMS;
    unsigned short* Y2A    = WihTbf + WTB_ELEMS;
    float* out = (float*)d_out;

    hipLaunchKernelGGL(k_prep, dim3(NB_PREP), dim3(256), 0, stream,
                       A, W, seq, Wih, Abf, Wbf, spad, WihTbf, rowsum);
    hipLaunchKernelGGL(k_gcn1, dim3(NMT*BT), dim3(256), 0, stream,
                       Abf, Wbf, spad, bias, w2, bias2, rowsum, Y1);
    hipLaunchKernelGGL(k_gcn2, dim3(NMT, 12), dim3(256), 0, stream, Abf, Y1, Y2A);
    hipLaunchKernelGGL(k_xwm, dim3(NBTF), dim3(64), 0, stream, Y2A, WihTbf, xW);
    hipLaunchKernelGGL(k_lstm, dim3(BB), dim3(64), 0, stream, xW, Whh, bih, bhh, h0, c0, s_sig);
    hipLaunchKernelGGL(k_heads, dim3((KK*BB*NN + 255)/256), dim3(256), 0, stream, fcw, fcb, s_sig, out);
}